// Round 8
// baseline (14979.538 us; speedup 1.0000x reference)
//
#include <hip/hip_runtime.h>
#include <hip/hip_cooperative_groups.h>

namespace cg = cooperative_groups;

#define VOCAB   32000
#define DIM     512
#define HDIM    512
#define BATCH   32
#define TSTEPS  128
#define TOPKN   5
#define CAND    8
#define BOSTOK  1
#define ALPHA   0.2f
#define G3H     1536

#define NBLK    256
#define NTHR    256
#define GEMMBLK 250
#define CPB     128

typedef unsigned long long u64;
typedef __bf16 bf16x8 __attribute__((ext_vector_type(8)));
typedef float  f32x4  __attribute__((ext_vector_type(4)));

// ---------------- shared helpers ----------------
__device__ __forceinline__ bool better(float v1, int i1, float v2, int i2) {
    return (v1 > v2) || (v1 == v2 && i1 < i2);   // value desc, index asc
}

__device__ __forceinline__ void ins5(float (&lv)[TOPKN], int (&li)[TOPKN], float v, int i) {
    if (better(v, i, lv[4], li[4])) {
        lv[4] = v; li[4] = i;
#pragma unroll
        for (int q = 4; q > 0; --q) {
            if (better(lv[q], li[q], lv[q - 1], li[q - 1])) {
                float tv = lv[q]; lv[q] = lv[q - 1]; lv[q - 1] = tv;
                int   ti = li[q]; li[q] = li[q - 1]; li[q - 1] = ti;
            }
        }
    }
}

__device__ __forceinline__ void ins8(float (&lv)[CAND], int (&li)[CAND], float v, int i) {
    if (better(v, i, lv[CAND - 1], li[CAND - 1])) {
        lv[CAND - 1] = v; li[CAND - 1] = i;
#pragma unroll
        for (int q = CAND - 1; q > 0; --q) {
            if (better(lv[q], li[q], lv[q - 1], li[q - 1])) {
                float tv = lv[q]; lv[q] = lv[q - 1]; lv[q - 1] = tv;
                int   ti = li[q]; li[q] = li[q - 1]; li[q - 1] = ti;
            }
        }
    }
}

__device__ __forceinline__ unsigned f2bf(float f) {   // f32 -> bf16 RNE
    unsigned u = __float_as_uint(f);
    return (u + 0x7FFFu + ((u >> 16) & 1u)) >> 16;
}

// ---- agent-scope (MALL-coherent) atomics for cross-block mutable state ----
__device__ __forceinline__ u64 aldu64(const u64* p) {
    return __hip_atomic_load(p, __ATOMIC_RELAXED, __HIP_MEMORY_SCOPE_AGENT);
}
__device__ __forceinline__ void astu64(u64* p, u64 v) {
    __hip_atomic_store(p, v, __ATOMIC_RELAXED, __HIP_MEMORY_SCOPE_AGENT);
}
__device__ __forceinline__ float aldf(const float* p) {
    return __hip_atomic_load(p, __ATOMIC_RELAXED, __HIP_MEMORY_SCOPE_AGENT);
}
__device__ __forceinline__ void astf(float* p, float v) {
    __hip_atomic_store(p, v, __ATOMIC_RELAXED, __HIP_MEMORY_SCOPE_AGENT);
}
__device__ __forceinline__ unsigned aldu32(const unsigned* p) {
    return __hip_atomic_load(p, __ATOMIC_RELAXED, __HIP_MEMORY_SCOPE_AGENT);
}
__device__ __forceinline__ void astu32(unsigned* p, unsigned v) {
    __hip_atomic_store(p, v, __ATOMIC_RELAXED, __HIP_MEMORY_SCOPE_AGENT);
}

// per-thread flag poll: each thread waits on its OWN flag word (no contention)
__device__ __forceinline__ void pollge(const unsigned* f, unsigned tgt) {
    unsigned v = aldu32(f);
    long g = 0;
    while (v < tgt && g < 10000000L) {   // bounded: no hang
        __builtin_amdgcn_s_sleep(2);
        v = aldu32(f);
        ++g;
    }
}

// block-wide: drain stores, then one thread publishes this block's flag
__device__ __forceinline__ void signalF(unsigned* f, unsigned val, int tid) {
    asm volatile("s_waitcnt vmcnt(0) lgkmcnt(0)" ::: "memory");
    __syncthreads();
    if (tid == 0) astu32(f, val);
}

// =====================================================================
// ============ round-8: persistent kernel, per-block flags ============
// =====================================================================

struct L5 {
    union {
        float protile[64][129];               // prologue scratch
        struct {
            u64      h2r[BATCH][256];         // raw h2 (f32 pairs)   64 KB
            unsigned hbf[BATCH][256];         // bf16-packed, XOR-swz 32 KB
            float pwv[4][BATCH][TOPKN];
            int   pwi[4][BATCH][TOPKN];
            float xgs[BATCH][6];
            int   sel[BATCH];
            u64   m8[4][CAND];
            int   c8[CAND];
            float e8[CAND];
        } r;
    };
};

__device__ void prologue5(L5& s, int j, int tid,
    const float* __restrict__ Wo, const float* __restrict__ U,
    const float* __restrict__ Wx, const float* __restrict__ ctx,
    unsigned* __restrict__ WoPk, float* __restrict__ WoT,
    float* __restrict__ UT, float* __restrict__ WxT, u64* __restrict__ h2x0)
{
    if (tid < BATCH) {   // h2_{-1} = ctx; block j owns h-cols {2j, 2j+1}
        const float lo = ctx[tid * HDIM + 2 * j];
        const float hi = ctx[tid * HDIM + 2 * j + 1];
        astu64(&h2x0[tid * 256 + j],
               ((u64)__float_as_uint(hi) << 32) | __float_as_uint(lo));
    }
    for (int i = tid; i < 6 * DIM; i += NTHR) {   // U_T / Wx_T rows (6 gate-cols)
        const int rr = i >> 9, k = i & 511;
        const int gc = (rr >> 1) * HDIM + 2 * j + (rr & 1);
        UT[(size_t)gc * DIM + k]  = U[(size_t)k * G3H + gc];
        WxT[(size_t)gc * DIM + k] = Wx[(size_t)k * G3H + gc];
    }
    if (j < GEMMBLK) {
        for (int chunk = 0; chunk < 8; ++chunk) {
            const int k0 = chunk * 64;
            __syncthreads();
#pragma unroll
            for (int it = 0; it < 8; ++it) {      // coalesced f32 tile [64][128]
                const int idx = tid + it * NTHR;
                const int kk = idx >> 5, c4 = (idx & 31) << 2;
                const float4 v = *(const float4*)(Wo + (size_t)(k0 + kk) * VOCAB + j * CPB + c4);
                s.protile[kk][c4] = v.x; s.protile[kk][c4 + 1] = v.y;
                s.protile[kk][c4 + 2] = v.z; s.protile[kk][c4 + 3] = v.w;
            }
            __syncthreads();
            {   // Wo_T f32 (exact, for SEL rescore)
                const int kh = tid >> 7, c = tid & 127;
                float* dst = WoT + ((size_t)j * CPB + c) * DIM + k0 + kh * 32;
#pragma unroll
                for (int kk = 0; kk < 32; ++kk) dst[kk] = s.protile[kh * 32 + kk][c];
            }
            // Wo packed bf16 in MFMA B-frag order (proven r3-r7)
#pragma unroll
            for (int uu = 0; uu < 4; ++uu) {
                const int u = tid + uu * NTHR;
                const int kss = u >> 9, nt = (u >> 6) & 7, ll = u & 63;
                const int kb = kss * 32 + ((ll >> 4) << 3);
                const int c  = nt * 16 + (ll & 15);
                unsigned d[4];
#pragma unroll
                for (int e2 = 0; e2 < 4; ++e2) {
                    const unsigned lo = f2bf(s.protile[kb + 2 * e2][c]);
                    const unsigned hi = f2bf(s.protile[kb + 2 * e2 + 1][c]);
                    d[e2] = lo | (hi << 16);
                }
                const int ksg = chunk * 2 + kss;
                uint4* dst = (uint4*)WoPk + ((((size_t)j * 16 + ksg) * 8 + nt) * 64 + ll);
                *dst = *(const uint4*)d;
            }
        }
    }
}

// hg_0 = ctx @ U + b_r  (prologue only; published via grid.sync)
__device__ __forceinline__ void hg_glb(int j, int tid, const float* __restrict__ hsrc,
                                       const float* __restrict__ UT,
                                       const float* __restrict__ b_r, float* __restrict__ hg)
{
    if (tid < 192) {
        const int g  = j * 192 + tid;
        const int bb = j >> 3;
        const int c  = 192 * (j & 7) + tid;
        const float4* hp = (const float4*)(hsrc + (size_t)bb * HDIM);
        const float4* up = (const float4*)(UT + (size_t)c * DIM);
        float a0 = b_r[c], a1 = 0.f, a2 = 0.f, a3 = 0.f;
#pragma unroll 4
        for (int i = 0; i < 128; i += 4) {
            float4 h0 = hp[i],     u0 = up[i];
            float4 h1 = hp[i + 1], u1 = up[i + 1];
            float4 h2v = hp[i + 2], u2 = up[i + 2];
            float4 h3 = hp[i + 3], u3 = up[i + 3];
            a0 = fmaf(h0.x, u0.x, fmaf(h0.y, u0.y, fmaf(h0.z, u0.z, fmaf(h0.w, u0.w, a0))));
            a1 = fmaf(h1.x, u1.x, fmaf(h1.y, u1.y, fmaf(h1.z, u1.z, fmaf(h1.w, u1.w, a1))));
            a2 = fmaf(h2v.x, u2.x, fmaf(h2v.y, u2.y, fmaf(h2v.z, u2.z, fmaf(h2v.w, u2.w, a2))));
            a3 = fmaf(h3.x, u3.x, fmaf(h3.y, u3.y, fmaf(h3.z, u3.z, fmaf(h3.w, u3.w, a3))));
        }
        astf(&hg[g], (a0 + a1) + (a2 + a3));
    }
}

// SEL (leads j<32, t>0): merge pvx -> top8 -> exact rescore -> selFW[b] = {t|sel}
__device__ void sel_phase(L5& s, int b, int tid, int t,
    const float* __restrict__ WoT, const float* __restrict__ bo,
    const int* __restrict__ rix, const u64* __restrict__ h2in,
    const u64* __restrict__ pvx, u64* __restrict__ selFW)
{
    float lv[TOPKN]; int li[TOPKN];
#pragma unroll
    for (int q = 0; q < TOPKN; ++q) { lv[q] = -INFINITY; li[q] = 0x7fffffff; }
    const u64* pb = &pvx[(size_t)b * (GEMMBLK * TOPKN)];
    for (int e = tid; e < GEMMBLK * TOPKN; e += NTHR) {   // <=5/thread: lossless
        const u64 v = aldu64(pb + e);
        ins5(lv, li, __uint_as_float((unsigned)(v >> 32)), (int)(unsigned)v);
    }
    float v8[CAND]; int i8[CAND];
#pragma unroll
    for (int q = 0; q < CAND; ++q) {
        v8[q] = (q < TOPKN) ? lv[q] : -INFINITY;
        i8[q] = (q < TOPKN) ? li[q] : 0x7fffffff;
    }
#pragma unroll
    for (int m = 1; m < 64; m <<= 1) {
#pragma unroll
        for (int q = 0; q < CAND; ++q) {
            const float ov = __shfl_xor(v8[q], m);
            const int   oi = __shfl_xor(i8[q], m);
            ins8(v8, i8, ov, oi);
        }
    }
    if ((tid & 63) == 0) {
#pragma unroll
        for (int q = 0; q < CAND; ++q)
            s.r.m8[tid >> 6][q] = ((u64)__float_as_uint(v8[q]) << 32) | (unsigned)i8[q];
    }
    __syncthreads();
    if (tid == 0) {
        float f8[CAND]; int fi[CAND];
#pragma unroll
        for (int q = 0; q < CAND; ++q) { f8[q] = -INFINITY; fi[q] = 0x7fffffff; }
#pragma unroll
        for (int w2 = 0; w2 < 4; ++w2)
#pragma unroll
            for (int q = 0; q < CAND; ++q) {
                const u64 v = s.r.m8[w2][q];
                ins8(f8, fi, __uint_as_float((unsigned)(v >> 32)), (int)(unsigned)v);
            }
#pragma unroll
        for (int q = 0; q < CAND; ++q) s.r.c8[q] = fi[q];
    }
    __syncthreads();
    {   // exact rescore: 8 groups x 32 lanes, coalesced WoT rows
        const int gp = tid >> 5, sub = tid & 31;
        const int cnd = s.r.c8[gp];
        const float4* wp = (const float4*)(WoT + (size_t)cnd * DIM) + sub * 4;
        const u64* hp = &h2in[(size_t)b * 256 + sub * 8];
        float a = 0.f;
#pragma unroll
        for (int ii = 0; ii < 4; ++ii) {
            const float4 wv = wp[ii];
            const u64 hA = aldu64(hp + 2 * ii);
            const u64 hB = aldu64(hp + 2 * ii + 1);
            a = fmaf(__uint_as_float((unsigned)hA), wv.x,
                fmaf(__uint_as_float((unsigned)(hA >> 32)), wv.y,
                fmaf(__uint_as_float((unsigned)hB), wv.z,
                fmaf(__uint_as_float((unsigned)(hB >> 32)), wv.w, a))));
        }
#pragma unroll
        for (int m = 1; m < 32; m <<= 1) a += __shfl_xor(a, m);
        if (sub == 0) s.r.e8[gp] = a + bo[cnd];
    }
    __syncthreads();
    if (tid == 0) {
        float lv5[TOPKN]; int li5[TOPKN];
#pragma unroll
        for (int q = 0; q < TOPKN; ++q) { lv5[q] = -INFINITY; li5[q] = 0x7fffffff; }
#pragma unroll
        for (int q = 0; q < CAND; ++q) ins5(lv5, li5, s.r.e8[q], s.r.c8[q]);
        const int ridx = rix[(t - 1) * BATCH + b];
        int sb = li5[0];
#pragma unroll
        for (int q = 1; q < TOPKN; ++q) if (ridx == q) sb = li5[q];
        // payload + flag in ONE atomic u64: hi = step, lo = sel
        astu64(&selFW[b], ((u64)(unsigned)t << 32) | (unsigned)sb);
    }
}

// GATE (all blocks): s.r.sel pre-filled; xg dots + GRU -> publish h2_t
__device__ void gateP(L5& s, int j, int tid, int t,
    const float* __restrict__ E, const float* __restrict__ WxT,
    const float* __restrict__ b_i, const float* __restrict__ hg,
    const u64* __restrict__ h2in, u64* __restrict__ h2out)
{
    __syncthreads();   // sel visible to all
    if (tid < 192) {
        const int bb = tid & 31, pp = tid >> 5;
        const int gc = (pp >> 1) * HDIM + 2 * j + (pp & 1);
        const float4* er = (const float4*)(E + (size_t)s.r.sel[bb] * DIM);
        const float4* wx = (const float4*)(WxT + (size_t)gc * DIM);
        float a0 = b_i[gc], a1 = 0.f, a2 = 0.f, a3 = 0.f;
#pragma unroll 4
        for (int i = 0; i < 128; i += 4) {
            float4 e0 = er[i], w0 = wx[i];
            float4 e1 = er[i + 1], w1 = wx[i + 1];
            float4 e2 = er[i + 2], w2 = wx[i + 2];
            float4 e3 = er[i + 3], w3 = wx[i + 3];
            e0.x = e0.x > 0.f ? e0.x : ALPHA * e0.x; e0.y = e0.y > 0.f ? e0.y : ALPHA * e0.y;
            e0.z = e0.z > 0.f ? e0.z : ALPHA * e0.z; e0.w = e0.w > 0.f ? e0.w : ALPHA * e0.w;
            e1.x = e1.x > 0.f ? e1.x : ALPHA * e1.x; e1.y = e1.y > 0.f ? e1.y : ALPHA * e1.y;
            e1.z = e1.z > 0.f ? e1.z : ALPHA * e1.z; e1.w = e1.w > 0.f ? e1.w : ALPHA * e1.w;
            e2.x = e2.x > 0.f ? e2.x : ALPHA * e2.x; e2.y = e2.y > 0.f ? e2.y : ALPHA * e2.y;
            e2.z = e2.z > 0.f ? e2.z : ALPHA * e2.z; e2.w = e2.w > 0.f ? e2.w : ALPHA * e2.w;
            e3.x = e3.x > 0.f ? e3.x : ALPHA * e3.x; e3.y = e3.y > 0.f ? e3.y : ALPHA * e3.y;
            e3.z = e3.z > 0.f ? e3.z : ALPHA * e3.z; e3.w = e3.w > 0.f ? e3.w : ALPHA * e3.w;
            a0 = fmaf(e0.x, w0.x, fmaf(e0.y, w0.y, fmaf(e0.z, w0.z, fmaf(e0.w, w0.w, a0))));
            a1 = fmaf(e1.x, w1.x, fmaf(e1.y, w1.y, fmaf(e1.z, w1.z, fmaf(e1.w, w1.w, a1))));
            a2 = fmaf(e2.x, w2.x, fmaf(e2.y, w2.y, fmaf(e2.z, w2.z, fmaf(e2.w, w2.w, a2))));
            a3 = fmaf(e3.x, w3.x, fmaf(e3.y, w3.y, fmaf(e3.z, w3.z, fmaf(e3.w, w3.w, a3))));
        }
        s.r.xgs[bb][pp] = (a0 + a1) + (a2 + a3);
    }
    __syncthreads();
    if (tid < 64) {
        const int bb = tid >> 1, q = tid & 1, hc = 2 * j + q;
        const u64 hv = aldu64(&h2in[bb * 256 + j]);
        const float hold = q ? __uint_as_float((unsigned)(hv >> 32))
                             : __uint_as_float((unsigned)hv);
        const float xz = s.r.xgs[bb][q], xr = s.r.xgs[bb][2 + q], xh = s.r.xgs[bb][4 + q];
        const float hz  = aldf(&hg[bb * G3H + hc]);
        const float hr_ = aldf(&hg[bb * G3H + HDIM + hc]);
        const float hh  = aldf(&hg[bb * G3H + 2 * HDIM + hc]);
        const float z  = 1.f / (1.f + expf(-(xz + hz)));
        const float r  = 1.f / (1.f + expf(-(xr + hr_)));
        const float cd = tanhf(xh + r * hh);
        const float nh = z * hold + (1.f - z) * cd;
        const float ph = __shfl_xor(nh, 1);
        if (q == 0)
            astu64(&h2out[bb * 256 + j],
                   ((u64)__float_as_uint(ph) << 32) | __float_as_uint(nh));
    }
}

// GEMM (all blocks): stage h2, MFMA logits, topk partials, hg_{t+1}  (round-5 proven)
__device__ void phA5(L5& s, int j, int tid, int t,
    const unsigned* __restrict__ WoPk, const float* __restrict__ bo,
    const float* __restrict__ UT, const float* __restrict__ b_r,
    const u64* __restrict__ h2in, float* __restrict__ out,
    float* __restrict__ hg, u64* __restrict__ pvx)
{
#pragma unroll 4
    for (int q = 0; q < BATCH; ++q) {
        const u64 v = aldu64(&h2in[q * 256 + tid]);
        s.r.h2r[q][tid] = v;
        const float lo = __uint_as_float((unsigned)v);
        const float hi = __uint_as_float((unsigned)(v >> 32));
        s.r.hbf[q][tid ^ ((q & 7) << 2)] = f2bf(lo) | (f2bf(hi) << 16);  // XOR-swz
    }
    __syncthreads();
    const int w = tid >> 6, l = tid & 63;
    if (j < GEMMBLK) {
        f32x4 acc[2][2];
        acc[0][0] = {0.f,0.f,0.f,0.f}; acc[0][1] = {0.f,0.f,0.f,0.f};
        acc[1][0] = {0.f,0.f,0.f,0.f}; acc[1][1] = {0.f,0.f,0.f,0.f};
        const uint4* wpk = (const uint4*)WoPk;
        const size_t base = (size_t)j * 8192 + l;
        const int r0 = l & 15, r1 = 16 + (l & 15);
        const int ko = (l >> 4) << 2;
        const int swz = (r0 & 7) << 2;
        uint4 vb[8];
#pragma unroll
        for (int pf = 0; pf < 4; ++pf) {           // depth-4 prefetch
            vb[2*pf]   = wpk[base + (size_t)(pf * 8 + 2 * w)     * 64];
            vb[2*pf+1] = wpk[base + (size_t)(pf * 8 + 2 * w + 1) * 64];
        }
#pragma unroll
        for (int ks = 0; ks < 16; ++ks) {
            const int sl2 = (ks & 3) * 2;
            const uint4 b0 = vb[sl2], b1 = vb[sl2 + 1];
            const uint4 a0 = *(const uint4*)&s.r.hbf[r0][(ks * 16 + ko) ^ swz];
            const uint4 a1 = *(const uint4*)&s.r.hbf[r1][(ks * 16 + ko) ^ swz];
            if (ks < 12) {
                vb[sl2]     = wpk[base + (size_t)((ks + 4) * 8 + 2 * w)     * 64];
                vb[sl2 + 1] = wpk[base + (size_t)((ks + 4) * 8 + 2 * w + 1) * 64];
            }
            const bf16x8 A0 = __builtin_bit_cast(bf16x8, a0);
            const bf16x8 A1 = __builtin_bit_cast(bf16x8, a1);
            const bf16x8 B0 = __builtin_bit_cast(bf16x8, b0);
            const bf16x8 B1 = __builtin_bit_cast(bf16x8, b1);
            acc[0][0] = __builtin_amdgcn_mfma_f32_16x16x32_bf16(A0, B0, acc[0][0], 0, 0, 0);
            acc[0][1] = __builtin_amdgcn_mfma_f32_16x16x32_bf16(A0, B1, acc[0][1], 0, 0, 0);
            acc[1][0] = __builtin_amdgcn_mfma_f32_16x16x32_bf16(A1, B0, acc[1][0], 0, 0, 0);
            acc[1][1] = __builtin_amdgcn_mfma_f32_16x16x32_bf16(A1, B1, acc[1][1], 0, 0, 0);
        }
        const int c0 = j * CPB + (2 * w) * 16 + (l & 15);
        const int c1 = j * CPB + (2 * w + 1) * 16 + (l & 15);
        const float bo0 = bo[c0], bo1 = bo[c1];
#pragma unroll
        for (int m = 0; m < 2; ++m) {
#pragma unroll
            for (int r = 0; r < 4; ++r) {
                const int b = 16 * m + ((l >> 4) << 2) + r;
                const float v0 = acc[m][0][r] + bo0;
                const float v1 = acc[m][1][r] + bo1;
                __builtin_nontemporal_store(v0, out + ((size_t)b * TSTEPS + t) * VOCAB + c0);
                __builtin_nontemporal_store(v1, out + ((size_t)b * TSTEPS + t) * VOCAB + c1);
                float lv[TOPKN]; int li[TOPKN];
#pragma unroll
                for (int q = 0; q < TOPKN; ++q) { lv[q] = -INFINITY; li[q] = 0x7fffffff; }
                ins5(lv, li, v0, c0);
                ins5(lv, li, v1, c1);
#pragma unroll
                for (int mask = 1; mask < 16; mask <<= 1) {
                    float ov[TOPKN]; int oi[TOPKN];
#pragma unroll
                    for (int q = 0; q < TOPKN; ++q) {
                        ov[q] = __shfl_xor(lv[q], mask);
                        oi[q] = __shfl_xor(li[q], mask);
                    }
#pragma unroll
                    for (int q = 0; q < TOPKN; ++q) ins5(lv, li, ov[q], oi[q]);
                }
                if ((l & 15) == 0) {
#pragma unroll
                    for (int q = 0; q < TOPKN; ++q) { s.r.pwv[w][b][q] = lv[q]; s.r.pwi[w][b][q] = li[q]; }
                }
            }
        }
    }
    // hg_{t+1} from LDS-staged h2 (broadcast reads, per-lane UT rows)
    if (tid < 192) {
        const int g  = j * 192 + tid;
        const int bb = j >> 3;
        const int c  = 192 * (j & 7) + tid;
        const u64* hr = s.r.h2r[bb];
        const float4* up = (const float4*)(UT + (size_t)c * DIM);
        float a0 = b_r[c], a1 = 0.f;
#pragma unroll 4
        for (int i = 0; i < 128; i += 2) {
            const float4 u0 = up[i];
            const float2 hA = __builtin_bit_cast(float2, hr[2 * i]);
            const float2 hB = __builtin_bit_cast(float2, hr[2 * i + 1]);
            const float4 u1 = up[i + 1];
            const float2 hC = __builtin_bit_cast(float2, hr[2 * i + 2]);
            const float2 hD = __builtin_bit_cast(float2, hr[2 * i + 3]);
            a0 = fmaf(hA.x, u0.x, fmaf(hA.y, u0.y, fmaf(hB.x, u0.z, fmaf(hB.y, u0.w, a0))));
            a1 = fmaf(hC.x, u1.x, fmaf(hC.y, u1.y, fmaf(hD.x, u1.z, fmaf(hD.y, u1.w, a1))));
        }
        astf(&hg[g], a0 + a1);
    }
    __syncthreads();
    if (j < GEMMBLK && tid < BATCH) {
        float lv[TOPKN]; int li[TOPKN];
#pragma unroll
        for (int q = 0; q < TOPKN; ++q) { lv[q] = -INFINITY; li[q] = 0x7fffffff; }
#pragma unroll
        for (int w4 = 0; w4 < 4; ++w4)
#pragma unroll
            for (int q = 0; q < TOPKN; ++q) ins5(lv, li, s.r.pwv[w4][tid][q], s.r.pwi[w4][tid][q]);
        const size_t base = ((size_t)tid * GEMMBLK + j) * TOPKN;
#pragma unroll
        for (int q = 0; q < TOPKN; ++q)
            astu64(&pvx[base + q], ((u64)__float_as_uint(lv[q]) << 32) | (unsigned)li[q]);
    }
}

static __global__ void __launch_bounds__(NTHR, 1)
gru8(const float* __restrict__ E,  const float* __restrict__ Wx,
     const float* __restrict__ U,  const float* __restrict__ b_i,
     const float* __restrict__ b_r, const float* __restrict__ Wo,
     const float* __restrict__ bo, const float* __restrict__ ctx,
     const int* __restrict__ rix,  float* __restrict__ out,
     unsigned* __restrict__ WoPk,  float* __restrict__ WoT,
     float* __restrict__ UT,       float* __restrict__ WxT,
     u64* __restrict__ h2x,        float* __restrict__ hg,
     u64* __restrict__ pvx,        unsigned* __restrict__ flagB,
     u64* __restrict__ selFW)
{
    cg::grid_group grid = cg::this_grid();
    extern __shared__ char smem_raw[];
    L5& s = *(L5*)smem_raw;
    const int j = blockIdx.x, tid = threadIdx.x;

    prologue5(s, j, tid, Wo, U, Wx, ctx, WoPk, WoT, UT, WxT, h2x);  // ctx -> h2x buf0
    grid.sync();                        // publish RO arrays (once)
    hg_glb(j, tid, ctx, UT, b_r, hg);   // hg_0
    grid.sync();                        // publish hg_0 (once)

    for (int t = 0; t < TSTEPS; ++t) {
        const u64* h2prev = h2x + (t & 1) * 8192;         // h2_{t-1}
        u64*       h2cur  = h2x + ((t & 1) ^ 1) * 8192;   // h2_t
        if (t > 0) {
            if (j < BATCH) {
                if (tid < GEMMBLK) pollge(&flagB[tid], 2u * (unsigned)t);  // partials t-1
                __syncthreads();
                sel_phase(s, j, tid, t, WoT, bo, rix, h2prev, pvx, selFW);
            }
            if (tid < BATCH) {   // all blocks: wait sel_t, capture payload
                u64 v = aldu64(&selFW[tid]);
                long g = 0;
                while ((unsigned)(v >> 32) < (unsigned)t && g < 10000000L) {
                    __builtin_amdgcn_s_sleep(2);
                    v = aldu64(&selFW[tid]);
                    ++g;
                }
                s.r.sel[tid] = (int)(unsigned)v;
            }
        } else {
            if (tid < BATCH) s.r.sel[tid] = BOSTOK;
        }
        gateP(s, j, tid, t, E, WxT, b_i, hg, h2prev, h2cur);
        signalF(&flagB[j], 2u * (unsigned)t + 1u, tid);      // h2_t ready (this block)
        if (tid < NBLK) pollge(&flagB[tid], 2u * (unsigned)t + 1u);
        __syncthreads();
        phA5(s, j, tid, t, WoPk, bo, UT, b_r, h2cur, out, hg, pvx);
        signalF(&flagB[j], 2u * (unsigned)t + 2u, tid);      // partials_t ready
    }
}

// =====================================================================
// ============== round-7 multi-kernel fallback (proven) ===============
// =====================================================================

static __global__ void __launch_bounds__(NTHR, 1)
kProlog(const float* __restrict__ Wo, const float* __restrict__ U,
        const float* __restrict__ Wx,
        unsigned* __restrict__ WoPk, float* __restrict__ WoT,
        float* __restrict__ UT, float* __restrict__ WxT)
{
    __shared__ float tile[64][129];
    const int j = blockIdx.x, tid = threadIdx.x;
    for (int i = tid; i < 6 * DIM; i += NTHR) {
        const int rr = i >> 9, k = i & 511;
        const int gc = (rr >> 1) * HDIM + 2 * j + (rr & 1);
        UT[(size_t)gc * DIM + k]  = U[(size_t)k * G3H + gc];
        WxT[(size_t)gc * DIM + k] = Wx[(size_t)k * G3H + gc];
    }
    if (j < GEMMBLK) {
        for (int chunk = 0; chunk < 8; ++chunk) {
            const int k0 = chunk * 64;
            __syncthreads();
#pragma unroll
            for (int it = 0; it < 8; ++it) {
                const int idx = tid + it * NTHR;
                const int kk = idx >> 5, c4 = (idx & 31) << 2;
                const float4 v = *(const float4*)(Wo + (size_t)(k0 + kk) * VOCAB + j * CPB + c4);
                tile[kk][c4] = v.x; tile[kk][c4 + 1] = v.y;
                tile[kk][c4 + 2] = v.z; tile[kk][c4 + 3] = v.w;
            }
            __syncthreads();
            {
                const int kh = tid >> 7, c = tid & 127;
                float* dst = WoT + ((size_t)j * CPB + c) * DIM + k0 + kh * 32;
#pragma unroll
                for (int kk = 0; kk < 32; ++kk) dst[kk] = tile[kh * 32 + kk][c];
            }
#pragma unroll
            for (int uu = 0; uu < 4; ++uu) {
                const int u = tid + uu * NTHR;
                const int kss = u >> 9, nt = (u >> 6) & 7, ll = u & 63;
                const int kb = kss * 32 + ((ll >> 4) << 3);
                const int c  = nt * 16 + (ll & 15);
                unsigned d[4];
#pragma unroll
                for (int e2 = 0; e2 < 4; ++e2) {
                    const unsigned lo = f2bf(tile[kb + 2 * e2][c]);
                    const unsigned hi = f2bf(tile[kb + 2 * e2 + 1][c]);
                    d[e2] = lo | (hi << 16);
                }
                const int ksg = chunk * 2 + kss;
                uint4* dst = (uint4*)WoPk + ((((size_t)j * 16 + ksg) * 8 + nt) * 64 + ll);
                *dst = *(const uint4*)d;
            }
        }
    }
}

static __global__ void __launch_bounds__(NTHR, 1)
kHg0(const float* __restrict__ ctx, const float* __restrict__ UT,
     const float* __restrict__ b_r, float* __restrict__ hg)
{
    const int j = blockIdx.x, tid = threadIdx.x;
    if (tid < 192) {
        const int g  = j * 192 + tid;
        const int bb = j >> 3;
        const int c  = 192 * (j & 7) + tid;
        const float4* hp = (const float4*)(ctx + (size_t)bb * HDIM);
        const float4* up = (const float4*)(UT + (size_t)c * DIM);
        float a0 = b_r[c], a1 = 0.f, a2 = 0.f, a3 = 0.f;
#pragma unroll 4
        for (int i = 0; i < 128; i += 4) {
            float4 h0 = hp[i],     u0 = up[i];
            float4 h1 = hp[i + 1], u1 = up[i + 1];
            float4 h2v = hp[i + 2], u2 = up[i + 2];
            float4 h3 = hp[i + 3], u3 = up[i + 3];
            a0 = fmaf(h0.x, u0.x, fmaf(h0.y, u0.y, fmaf(h0.z, u0.z, fmaf(h0.w, u0.w, a0))));
            a1 = fmaf(h1.x, u1.x, fmaf(h1.y, u1.y, fmaf(h1.z, u1.z, fmaf(h1.w, u1.w, a1))));
            a2 = fmaf(h2v.x, u2.x, fmaf(h2v.y, u2.y, fmaf(h2v.z, u2.z, fmaf(h2v.w, u2.w, a2))));
            a3 = fmaf(h3.x, u3.x, fmaf(h3.y, u3.y, fmaf(h3.z, u3.z, fmaf(h3.w, u3.w, a3))));
        }
        hg[g] = (a0 + a1) + (a2 + a3);
    }
}

static __global__ void __launch_bounds__(NTHR, 1)
kSel(int t, const float* __restrict__ WoT, const float* __restrict__ bo,
     const int* __restrict__ rix, const float* __restrict__ h2prev,
     const u64* __restrict__ pvx, unsigned* __restrict__ selw)
{
    __shared__ u64   m8[4][CAND];
    __shared__ int   c8[CAND];
    __shared__ float e8[CAND];
    const int b = blockIdx.x, tid = threadIdx.x;
    float lv[TOPKN]; int li[TOPKN];
#pragma unroll
    for (int q = 0; q < TOPKN; ++q) { lv[q] = -INFINITY; li[q] = 0x7fffffff; }
    const u64* pb = pvx + (size_t)b * (GEMMBLK * TOPKN);
    for (int e = tid; e < GEMMBLK * TOPKN; e += NTHR) {
        const u64 v = pb[e];
        ins5(lv, li, __uint_as_float((unsigned)(v >> 32)), (int)(unsigned)v);
    }
    float v8[CAND]; int i8[CAND];
#pragma unroll
    for (int q = 0; q < CAND; ++q) {
        v8[q] = (q < TOPKN) ? lv[q] : -INFINITY;
        i8[q] = (q < TOPKN) ? li[q] : 0x7fffffff;
    }
#pragma unroll
    for (int m = 1; m < 64; m <<= 1) {
#pragma unroll
        for (int q = 0; q < CAND; ++q) {
            const float ov = __shfl_xor(v8[q], m);
            const int   oi = __shfl_xor(i8[q], m);
            ins8(v8, i8, ov, oi);
        }
    }
    if ((tid & 63) == 0) {
#pragma unroll
        for (int q = 0; q < CAND; ++q)
            m8[tid >> 6][q] = ((u64)__float_as_uint(v8[q]) << 32) | (unsigned)i8[q];
    }
    __syncthreads();
    if (tid == 0) {
        float f8[CAND]; int fi[CAND];
#pragma unroll
        for (int q = 0; q < CAND; ++q) { f8[q] = -INFINITY; fi[q] = 0x7fffffff; }
#pragma unroll
        for (int w2 = 0; w2 < 4; ++w2)
#pragma unroll
            for (int q = 0; q < CAND; ++q) {
                const u64 v = m8[w2][q];
                ins8(f8, fi, __uint_as_float((unsigned)(v >> 32)), (int)(unsigned)v);
            }
#pragma unroll
        for (int q = 0; q < CAND; ++q) c8[q] = fi[q];
    }
    __syncthreads();
    {
        const int gp = tid >> 5, sub = tid & 31;
        const int cnd = c8[gp];
        const float4* wp = (const float4*)(WoT + (size_t)cnd * DIM) + sub * 4;
        const float4* hp = (const float4*)(h2prev + (size_t)b * HDIM) + sub * 4;
        float a = 0.f;
#pragma unroll
        for (int ii = 0; ii < 4; ++ii) {
            const float4 wv = wp[ii], hv = hp[ii];
            a = fmaf(hv.x, wv.x, fmaf(hv.y, wv.y, fmaf(hv.z, wv.z, fmaf(hv.w, wv.w, a))));
        }
#pragma unroll
        for (int m = 1; m < 32; m <<= 1) a += __shfl_xor(a, m);
        if (sub == 0) e8[gp] = a + bo[cnd];
    }
    __syncthreads();
    if (tid == 0) {
        float lv5[TOPKN]; int li5[TOPKN];
#pragma unroll
        for (int q = 0; q < TOPKN; ++q) { lv5[q] = -INFINITY; li5[q] = 0x7fffffff; }
#pragma unroll
        for (int q = 0; q < CAND; ++q) ins5(lv5, li5, e8[q], c8[q]);
        const int ridx = rix[(t - 1) * BATCH + b];
        int sb = li5[0];
#pragma unroll
        for (int q = 1; q < TOPKN; ++q) if (ridx == q) sb = li5[q];
        selw[b] = (unsigned)sb;
    }
}

struct GateLDS {
    float er[BATCH][516];
    float xgs[BATCH][6];
    int   sel[BATCH];
};

static __global__ void __launch_bounds__(NTHR, 1)
kGate(int t, const float* __restrict__ E, const float* __restrict__ WxT,
      const float* __restrict__ b_i, const float* __restrict__ ctx,
      const unsigned* __restrict__ selw, const float* __restrict__ hg,
      const float* __restrict__ h2prev, float* __restrict__ h2cur)
{
    extern __shared__ char raw[];
    GateLDS& s = *(GateLDS*)raw;
    const int j = blockIdx.x, tid = threadIdx.x;
    if (tid < BATCH)
        s.sel[tid] = (t == 0) ? BOSTOK : (int)selw[tid];
    __syncthreads();
    {
        const int b = tid >> 3, ch = tid & 7;
        const float4* src = (const float4*)(E + (size_t)s.sel[b] * DIM) + ch * 16;
        float* dst = &s.er[b][ch * 64];
#pragma unroll
        for (int i = 0; i < 16; ++i) {
            float4 v = src[i];
            v.x = v.x > 0.f ? v.x : ALPHA * v.x;
            v.y = v.y > 0.f ? v.y : ALPHA * v.y;
            v.z = v.z > 0.f ? v.z : ALPHA * v.z;
            v.w = v.w > 0.f ? v.w : ALPHA * v.w;
            *(float4*)(dst + 4 * i) = v;
        }
    }
    __syncthreads();
    if (tid < 192) {
        const int bb = tid & 31, pp = tid >> 5;
        const int gc = (pp >> 1) * HDIM + 2 * j + (pp & 1);
        const float4* er = (const float4*)&s.er[bb][0];
        const float4* wx = (const float4*)(WxT + (size_t)gc * DIM);
        float a0 = b_i[gc], a1 = 0.f, a2 = 0.f, a3 = 0.f;
#pragma unroll 4
        for (int i = 0; i < 128; i += 4) {
            const float4 e0 = er[i],     w0 = wx[i];
            const float4 e1 = er[i + 1], w1 = wx[i + 1];
            const float4 e2 = er[i + 2], w2 = wx[i + 2];
            const float4 e3 = er[i + 3], w3 = wx[i + 3];
            a0 = fmaf(e0.x, w0.x, fmaf(e0.y, w0.y, fmaf(e0.z, w0.z, fmaf(e0.w, w0.w, a0))));
            a1 = fmaf(e1.x, w1.x, fmaf(e1.y, w1.y, fmaf(e1.z, w1.z, fmaf(e1.w, w1.w, a1))));
            a2 = fmaf(e2.x, w2.x, fmaf(e2.y, w2.y, fmaf(e2.z, w2.z, fmaf(e2.w, w2.w, a2))));
            a3 = fmaf(e3.x, w3.x, fmaf(e3.y, w3.y, fmaf(e3.z, w3.z, fmaf(e3.w, w3.w, a3))));
        }
        s.xgs[bb][pp] = (a0 + a1) + (a2 + a3);
    }
    __syncthreads();
    if (tid < 64) {
        const int bb = tid >> 1, q = tid & 1, hc = 2 * j + q;
        const float hold = (t == 0) ? ctx[(size_t)bb * HDIM + hc]
                                    : h2prev[(size_t)bb * HDIM + hc];
        const float xz = s.xgs[bb][q], xr = s.xgs[bb][2 + q], xh = s.xgs[bb][4 + q];
        const float hz  = hg[(size_t)bb * G3H + hc];
        const float hr_ = hg[(size_t)bb * G3H + HDIM + hc];
        const float hh  = hg[(size_t)bb * G3H + 2 * HDIM + hc];
        const float z  = 1.f / (1.f + expf(-(xz + hz)));
        const float r  = 1.f / (1.f + expf(-(xr + hr_)));
        const float cd = tanhf(xh + r * hh);
        h2cur[(size_t)bb * HDIM + hc] = z * hold + (1.f - z) * cd;
    }
}

struct GemmLDS {
    u64      h2r[BATCH][256];
    unsigned hbf[BATCH][256];
    float pwv[4][BATCH][TOPKN];
    int   pwi[4][BATCH][TOPKN];
};

static __global__ void __launch_bounds__(NTHR, 1)
kGemm(int t, const unsigned* __restrict__ WoPk, const float* __restrict__ bo,
      const float* __restrict__ UT, const float* __restrict__ b_r,
      const float* __restrict__ h2in, float* __restrict__ out,
      float* __restrict__ hg, u64* __restrict__ pvx)
{
    extern __shared__ char raw[];
    GemmLDS& s = *(GemmLDS*)raw;
    const int j = blockIdx.x, tid = threadIdx.x;
#pragma unroll 4
    for (int q = 0; q < BATCH; ++q) {
        const float2 v = *(const float2*)&h2in[(size_t)q * HDIM + 2 * tid];
        s.h2r[q][tid] = __builtin_bit_cast(u64, v);
        s.hbf[q][tid ^ ((q & 7) << 2)] = f2bf(v.x) | (f2bf(v.y) << 16);
    }
    __syncthreads();
    const int w = tid >> 6, l = tid & 63;
    if (j < GEMMBLK) {
        f32x4 acc[2][2];
        acc[0][0] = {0.f,0.f,0.f,0.f}; acc[0][1] = {0.f,0.f,0.f,0.f};
        acc[1][0] = {0.f,0.f,0.f,0.f}; acc[1][1] = {0.f,0.f,0.f,0.f};
        const uint4* wpk = (const uint4*)WoPk;
        const size_t base = (size_t)j * 8192 + l;
        const int r0 = l & 15, r1 = 16 + (l & 15);
        const int ko = (l >> 4) << 2;
        const int swz = (r0 & 7) << 2;
        uint4 vb[8];
#pragma unroll
        for (int pf = 0; pf < 4; ++pf) {
            vb[2*pf]   = wpk[base + (size_t)(pf * 8 + 2 * w)     * 64];
            vb[2*pf+1] = wpk[base + (size_t)(pf * 8 + 2 * w + 1) * 64];
        }
#pragma unroll
        for (int ks = 0; ks < 16; ++ks) {
            const int sl2 = (ks & 3) * 2;
            const uint4 b0 = vb[sl2], b1 = vb[sl2 + 1];
            const uint4 a0 = *(const uint4*)&s.hbf[r0][(ks * 16 + ko) ^ swz];
            const uint4 a1 = *(const uint4*)&s.hbf[r1][(ks * 16 + ko) ^ swz];
            if (ks < 12) {
                vb[sl2]     = wpk[base + (size_t)((ks + 4) * 8 + 2 * w)     * 64];
                vb[sl2 + 1] = wpk[base + (size_t)((ks + 4) * 8 + 2 * w + 1) * 64];
            }
            const bf16x8 A0 = __builtin_bit_cast(bf16x8, a0);
            const bf16x8 A1 = __builtin_bit_cast(bf16x8, a1);
            const bf16x8 B0 = __builtin_bit_cast(bf16x8, b0);
            const bf16x8 B1 = __builtin_bit_cast(bf16x8, b1);
            acc[0][0] = __builtin_amdgcn_mfma_f32_16x16x32_bf16(A0, B0, acc[0][0], 0, 0, 0);
            acc[0][1] = __builtin_amdgcn_mfma_f32_16x16x32_bf16(A0, B1, acc[0][1], 0, 0, 0);
            acc[1][0] = __builtin_amdgcn_mfma_f32_16x16x32_bf16(A1, B0, acc[1][0], 0, 0, 0);
            acc[1][1] = __builtin_amdgcn_mfma_f32_16x16x32_bf16(A1, B1, acc[1][1], 0, 0, 0);
        }
        const int c0 = j * CPB + (2 * w) * 16 + (l & 15);
        const int c1 = j * CPB + (2 * w + 1) * 16 + (l & 15);
        const float bo0 = bo[c0], bo1 = bo[c1];
#pragma unroll
        for (int m = 0; m < 2; ++m) {
#pragma unroll
            for (int r = 0; r < 4; ++r) {
                const int b = 16 * m + ((l >> 4) << 2) + r;
                const float v0 = acc[m][0][r] + bo0;
                const float v1 = acc[m][1][r] + bo1;
                __builtin_nontemporal_store(v0, out + ((size_t)b * TSTEPS + t) * VOCAB + c0);
                __builtin_nontemporal_store(v1, out + ((size_t)b * TSTEPS + t) * VOCAB + c1);
                float lv[TOPKN]; int li[TOPKN];
#pragma unroll
                for (int q = 0; q < TOPKN; ++q) { lv[q] = -INFINITY; li[q] = 0x7fffffff; }
                ins5(lv, li, v0, c0);
                ins5(lv, li, v1, c1);
#pragma unroll
                for (int mask = 1; mask < 16; mask <<= 1) {
                    float ov[TOPKN]; int oi[TOPKN];
#pragma unroll
                    for (int q = 0; q < TOPKN; ++q) {
                        ov[q] = __shfl_xor(lv[q], mask);
                        oi[q] = __shfl_xor(li[q], mask);
                    }
#pragma unroll
                    for (int q = 0; q < TOPKN; ++q) ins5(lv, li, ov[q], oi[q]);
                }
                if ((l & 15) == 0) {
#pragma unroll
                    for (int q = 0; q < TOPKN; ++q) { s.pwv[w][b][q] = lv[q]; s.pwi[w][b][q] = li[q]; }
                }
            }
        }
    }
    if (tid < 192) {
        const int g  = j * 192 + tid;
        const int bb = j >> 3;
        const int c  = 192 * (j & 7) + tid;
        const float4* hr = (const float4*)&s.h2r[bb][0];
        const float4* up = (const float4*)(UT + (size_t)c * DIM);
        float a0 = b_r[c], a1 = 0.f, a2 = 0.f, a3 = 0.f;
#pragma unroll 4
        for (int i = 0; i < 128; i += 4) {
            const float4 u0 = up[i],     h0 = hr[i];
            const float4 u1 = up[i + 1], h1 = hr[i + 1];
            const float4 u2 = up[i + 2], h2v = hr[i + 2];
            const float4 u3 = up[i + 3], h3 = hr[i + 3];
            a0 = fmaf(h0.x, u0.x, fmaf(h0.y, u0.y, fmaf(h0.z, u0.z, fmaf(h0.w, u0.w, a0))));
            a1 = fmaf(h1.x, u1.x, fmaf(h1.y, u1.y, fmaf(h1.z, u1.z, fmaf(h1.w, u1.w, a1))));
            a2 = fmaf(h2v.x, u2.x, fmaf(h2v.y, u2.y, fmaf(h2v.z, u2.z, fmaf(h2v.w, u2.w, a2))));
            a3 = fmaf(h3.x, u3.x, fmaf(h3.y, u3.y, fmaf(h3.z, u3.z, fmaf(h3.w, u3.w, a3))));
        }
        hg[g] = (a0 + a1) + (a2 + a3);
    }
    __syncthreads();
    if (j < GEMMBLK && tid < BATCH) {
        float lv[TOPKN]; int li[TOPKN];
#pragma unroll
        for (int q = 0; q < TOPKN; ++q) { lv[q] = -INFINITY; li[q] = 0x7fffffff; }
#pragma unroll
        for (int w4 = 0; w4 < 4; ++w4)
#pragma unroll
            for (int q = 0; q < TOPKN; ++q) ins5(lv, li, s.pwv[w4][tid][q], s.pwi[w4][tid][q]);
        const size_t base = ((size_t)tid * GEMMBLK + j) * TOPKN;
#pragma unroll
        for (int q = 0; q < TOPKN; ++q)
            pvx[base + q] = ((u64)__float_as_uint(lv[q]) << 32) | (unsigned)li[q];
    }
}

// =====================================================================
extern "C" void kernel_launch(void* const* d_in, const int* in_sizes, int n_in,
                              void* d_out, int out_size, void* d_ws, size_t ws_size,
                              hipStream_t stream) {
    (void)in_sizes; (void)n_in; (void)out_size;
    const float* E   = (const float*)d_in[0];
    const float* Wx  = (const float*)d_in[1];
    const float* U   = (const float*)d_in[2];
    const float* b_i = (const float*)d_in[3];
    const float* b_r = (const float*)d_in[4];
    const float* Wo  = (const float*)d_in[5];
    const float* bo  = (const float*)d_in[6];
    const float* ctx = (const float*)d_in[7];
    const int*   rix = (const int*)d_in[8];
    float* out = (float*)d_out;

    int dev = 0;
    (void)hipGetDevice(&dev);
    int coopAttr = 0, numCU = 0;
    (void)hipDeviceGetAttribute(&coopAttr, hipDeviceAttributeCooperativeLaunch, dev);
    (void)hipDeviceGetAttribute(&numCU, hipDeviceAttributeMultiprocessorCount, dev);

    // ---- ws layout (bytes, 8B aligned; identical footprint to proven r5/r6) ----
    const size_t oWoPk = 0;            // 512*32000*2      = 32,768,000
    const size_t oWoT  = 32768000;     // 32000*512*4      = 65,536,000
    const size_t oUT   = 98304000;     // 1536*512*4       =  3,145,728
    const size_t oWxT  = 101449728;    // 1536*512*4       =  3,145,728
    const size_t oH2X  = 104595456;    // 2*32*256*8       =    131,072
    const size_t oHG   = 104726528;    // 32*1536*4        =    196,608
    const size_t oPVX  = 104923136;    // 32*250*5*8       =    320,000
    const size_t oBAR  = 105243136;    // flagB[256] u32 (1024B) + selFW[32] u64 (256B)
    const size_t oSEL  = 105245184;    // selw[32] (fallback path)
    const size_t need  = 105245312;    // == round-5/6 proven footprint

    char* w = (char*)d_ws;
    unsigned* WoPk = (unsigned*)(w + oWoPk);
    float* WoT  = (float*)(w + oWoT);
    float* UT   = (float*)(w + oUT);
    float* WxT  = (float*)(w + oWxT);
    u64*   h2x  = (u64*)(w + oH2X);
    float* hg   = (float*)(w + oHG);
    u64*   pvx  = (u64*)(w + oPVX);
    unsigned* flagB = (unsigned*)(w + oBAR);
    u64*      selFW = (u64*)(w + oBAR + 1024);
    unsigned* selw  = (unsigned*)(w + oSEL);

    bool launched = false;
    if (coopAttr && ws_size >= need) {
        const int LDSB = (int)sizeof(L5);
        (void)hipFuncSetAttribute((const void*)gru8,
                                  hipFuncAttributeMaxDynamicSharedMemorySize, LDSB);
        int maxBlk = 0;
        (void)hipOccupancyMaxActiveBlocksPerMultiprocessor(&maxBlk, gru8, NTHR, LDSB);
        if (maxBlk >= 1 && (long)maxBlk * numCU >= NBLK) {
            if (hipMemsetAsync((void*)flagB, 0, 2048, stream) == hipSuccess) {
                void* args[] = {&E, &Wx, &U, &b_i, &b_r, &Wo, &bo, &ctx, &rix, &out,
                                &WoPk, &WoT, &UT, &WxT, &h2x, &hg, &pvx, &flagB, &selFW};
                if (hipLaunchCooperativeKernel(gru8, dim3(NBLK), dim3(NTHR),
                                               args, (unsigned)LDSB, stream) == hipSuccess)
                    launched = true;
                else (void)hipGetLastError();
            } else (void)hipGetLastError();
        }
    }

    if (!launched && ws_size >= need) {
        // ---- proven round-7 multi-kernel path ----
        float* h2f = (float*)(w + oH2X);   // reuse as f32 [2][32][512]
        const int GATE_LDS = (int)sizeof(GateLDS);
        const int GEMM_LDS = (int)sizeof(GemmLDS);
        (void)hipFuncSetAttribute((const void*)kGate,
                                  hipFuncAttributeMaxDynamicSharedMemorySize, GATE_LDS);
        (void)hipFuncSetAttribute((const void*)kGemm,
                                  hipFuncAttributeMaxDynamicSharedMemorySize, GEMM_LDS);
        kProlog<<<dim3(NBLK), dim3(NTHR), 0, stream>>>(Wo, U, Wx, WoPk, WoT, UT, WxT);
        kHg0<<<dim3(NBLK), dim3(NTHR), 0, stream>>>(ctx, UT, b_r, hg);
        for (int t = 0; t < TSTEPS; ++t) {
            float*       h2cur  = h2f + (t & 1) * (BATCH * HDIM);
            const float* h2prev = h2f + ((t & 1) ^ 1) * (BATCH * HDIM);
            if (t > 0)
                kSel<<<dim3(BATCH), dim3(NTHR), 0, stream>>>(t, WoT, bo, rix,
                                                             h2prev, pvx, selw);
            kGate<<<dim3(NBLK), dim3(NTHR), GATE_LDS, stream>>>(t, E, WxT, b_i, ctx,
                                                                selw, hg, h2prev, h2cur);
            kGemm<<<dim3(NBLK), dim3(NTHR), GEMM_LDS, stream>>>(t, WoPk, bo, UT, b_r,
                                                                h2cur, out, hg, pvx);
        }
    }
}

// Round 9
// 14557.243 us; speedup vs baseline: 1.0290x; 1.0290x over previous
//
#include <hip/hip_runtime.h>

#define VOCAB   32000
#define DIM     512
#define HDIM    512
#define BATCH   32
#define TSTEPS  128
#define TOPKN   5
#define CAND    8
#define BOSTOK  1
#define ALPHA   0.2f
#define G3H     1536

#define NBLK    256
#define NTHR    256
#define GEMMBLK 250
#define CPB     128

typedef unsigned long long u64;
typedef __bf16 bf16x8 __attribute__((ext_vector_type(8)));
typedef float  f32x4  __attribute__((ext_vector_type(4)));

// ---------------- shared helpers ----------------
__device__ __forceinline__ bool better(float v1, int i1, float v2, int i2) {
    return (v1 > v2) || (v1 == v2 && i1 < i2);   // value desc, index asc
}

__device__ __forceinline__ void ins5(float (&lv)[TOPKN], int (&li)[TOPKN], float v, int i) {
    if (better(v, i, lv[4], li[4])) {
        lv[4] = v; li[4] = i;
#pragma unroll
        for (int q = 4; q > 0; --q) {
            if (better(lv[q], li[q], lv[q - 1], li[q - 1])) {
                float tv = lv[q]; lv[q] = lv[q - 1]; lv[q - 1] = tv;
                int   ti = li[q]; li[q] = li[q - 1]; li[q - 1] = ti;
            }
        }
    }
}

__device__ __forceinline__ void ins8(float (&lv)[CAND], int (&li)[CAND], float v, int i) {
    if (better(v, i, lv[CAND - 1], li[CAND - 1])) {
        lv[CAND - 1] = v; li[CAND - 1] = i;
#pragma unroll
        for (int q = CAND - 1; q > 0; --q) {
            if (better(lv[q], li[q], lv[q - 1], li[q - 1])) {
                float tv = lv[q]; lv[q] = lv[q - 1]; lv[q - 1] = tv;
                int   ti = li[q]; li[q] = li[q - 1]; li[q - 1] = ti;
            }
        }
    }
}

__device__ __forceinline__ unsigned f2bf(float f) {   // f32 -> bf16 RNE
    unsigned u = __float_as_uint(f);
    return (u + 0x7FFFu + ((u >> 16) & 1u)) >> 16;
}

// agent-scope atomics — ONLY for the intra-kernel selFW edge
__device__ __forceinline__ u64 aldu64(const u64* p) {
    return __hip_atomic_load(p, __ATOMIC_RELAXED, __HIP_MEMORY_SCOPE_AGENT);
}
__device__ __forceinline__ void astu64(u64* p, u64 v) {
    __hip_atomic_store(p, v, __ATOMIC_RELAXED, __HIP_MEMORY_SCOPE_AGENT);
}

// ---------------- prologue: WoPk / WoT / UT / WxT (proven r3-r8) ----------------
static __global__ void __launch_bounds__(NTHR, 1)
kProlog(const float* __restrict__ Wo, const float* __restrict__ U,
        const float* __restrict__ Wx,
        unsigned* __restrict__ WoPk, float* __restrict__ WoT,
        float* __restrict__ UT, float* __restrict__ WxT)
{
    __shared__ float tile[64][129];
    const int j = blockIdx.x, tid = threadIdx.x;
    for (int i = tid; i < 6 * DIM; i += NTHR) {
        const int rr = i >> 9, k = i & 511;
        const int gc = (rr >> 1) * HDIM + 2 * j + (rr & 1);
        UT[(size_t)gc * DIM + k]  = U[(size_t)k * G3H + gc];
        WxT[(size_t)gc * DIM + k] = Wx[(size_t)k * G3H + gc];
    }
    if (j < GEMMBLK) {
        for (int chunk = 0; chunk < 8; ++chunk) {
            const int k0 = chunk * 64;
            __syncthreads();
#pragma unroll
            for (int it = 0; it < 8; ++it) {
                const int idx = tid + it * NTHR;
                const int kk = idx >> 5, c4 = (idx & 31) << 2;
                const float4 v = *(const float4*)(Wo + (size_t)(k0 + kk) * VOCAB + j * CPB + c4);
                tile[kk][c4] = v.x; tile[kk][c4 + 1] = v.y;
                tile[kk][c4 + 2] = v.z; tile[kk][c4 + 3] = v.w;
            }
            __syncthreads();
            {
                const int kh = tid >> 7, c = tid & 127;
                float* dst = WoT + ((size_t)j * CPB + c) * DIM + k0 + kh * 32;
#pragma unroll
                for (int kk = 0; kk < 32; ++kk) dst[kk] = tile[kh * 32 + kk][c];
            }
#pragma unroll
            for (int uu = 0; uu < 4; ++uu) {
                const int u = tid + uu * NTHR;
                const int kss = u >> 9, nt = (u >> 6) & 7, ll = u & 63;
                const int kb = kss * 32 + ((ll >> 4) << 3);
                const int c  = nt * 16 + (ll & 15);
                unsigned d[4];
#pragma unroll
                for (int e2 = 0; e2 < 4; ++e2) {
                    const unsigned lo = f2bf(tile[kb + 2 * e2][c]);
                    const unsigned hi = f2bf(tile[kb + 2 * e2 + 1][c]);
                    d[e2] = lo | (hi << 16);
                }
                const int ksg = chunk * 2 + kss;
                uint4* dst = (uint4*)WoPk + ((((size_t)j * 16 + ksg) * 8 + nt) * 64 + ll);
                *dst = *(const uint4*)d;
            }
        }
    }
}

// =====================================================================
// ======== primary: kGateSel (SEL folded into GATE, 1 kernel) =========
// =====================================================================

struct GSLDS {
    float h2s[BATCH][516];   // staged h2_{t-1} (66 KB)
    float er[BATCH][516];    // staged leaky(E[sel]) (66 KB)
    float xgs[BATCH][6];
    float hgv[BATCH][6];
    int   sel[BATCH];
    u64   m8[4][CAND];
    int   c8[CAND];
    float e8[CAND];
};                           // ~134 KB dynamic

static __global__ void __launch_bounds__(NTHR, 1)
kGateSel(int t, const float* __restrict__ E, const float* __restrict__ WxT,
         const float* __restrict__ UT, const float* __restrict__ b_i,
         const float* __restrict__ b_r, const float* __restrict__ WoT,
         const float* __restrict__ bo, const int* __restrict__ rix,
         const float* __restrict__ ctx, const float* __restrict__ h2prev,
         float* __restrict__ h2cur, const u64* __restrict__ pvx,
         u64* __restrict__ selFW)
{
    extern __shared__ char raw[];
    GSLDS& s = *(GSLDS*)raw;
    const int j = blockIdx.x, tid = threadIdx.x;

    // 1) stage h2_{t-1} (or ctx) -> LDS, coalesced
    const float* hsrc = (t == 0) ? ctx : h2prev;
#pragma unroll
    for (int it = 0; it < 16; ++it) {
        const int i = tid + it * NTHR;          // 0..4095 float4
        const int r = i >> 7, c4 = i & 127;
        *(float4*)&s.h2s[r][c4 * 4] = ((const float4*)hsrc)[i];
    }
    __syncthreads();

    // 2) SEL (blocks 0..31, t>0): merge partials -> top8 -> exact rescore -> publish
    if (t > 0 && j < BATCH) {
        float lv[TOPKN]; int li[TOPKN];
#pragma unroll
        for (int q = 0; q < TOPKN; ++q) { lv[q] = -INFINITY; li[q] = 0x7fffffff; }
        const u64* pb = pvx + (size_t)j * (GEMMBLK * TOPKN);
        for (int e = tid; e < GEMMBLK * TOPKN; e += NTHR) {   // <=5/thread: lossless
            const u64 v = pb[e];
            ins5(lv, li, __uint_as_float((unsigned)(v >> 32)), (int)(unsigned)v);
        }
        float v8[CAND]; int i8[CAND];
#pragma unroll
        for (int q = 0; q < CAND; ++q) {
            v8[q] = (q < TOPKN) ? lv[q] : -INFINITY;
            i8[q] = (q < TOPKN) ? li[q] : 0x7fffffff;
        }
#pragma unroll
        for (int m = 1; m < 64; m <<= 1) {
#pragma unroll
            for (int q = 0; q < CAND; ++q) {
                const float ov = __shfl_xor(v8[q], m);
                const int   oi = __shfl_xor(i8[q], m);
                ins8(v8, i8, ov, oi);
            }
        }
        if ((tid & 63) == 0) {
#pragma unroll
            for (int q = 0; q < CAND; ++q)
                s.m8[tid >> 6][q] = ((u64)__float_as_uint(v8[q]) << 32) | (unsigned)i8[q];
        }
        __syncthreads();
        if (tid == 0) {
            float f8[CAND]; int fi[CAND];
#pragma unroll
            for (int q = 0; q < CAND; ++q) { f8[q] = -INFINITY; fi[q] = 0x7fffffff; }
#pragma unroll
            for (int w2 = 0; w2 < 4; ++w2)
#pragma unroll
                for (int q = 0; q < CAND; ++q) {
                    const u64 v = s.m8[w2][q];
                    ins8(f8, fi, __uint_as_float((unsigned)(v >> 32)), (int)(unsigned)v);
                }
#pragma unroll
            for (int q = 0; q < CAND; ++q) s.c8[q] = fi[q];
        }
        __syncthreads();
        {   // exact f32 rescore: 8 groups x 32 lanes; h2 from LDS, WoT coalesced
            const int gp = tid >> 5, sub = tid & 31;
            const int cnd = s.c8[gp];
            const float4* wp = (const float4*)(WoT + (size_t)cnd * DIM) + sub * 4;
            const float4* hp = (const float4*)&s.h2s[j][sub * 16];
            float a = 0.f;
#pragma unroll
            for (int ii = 0; ii < 4; ++ii) {
                const float4 wv = wp[ii], hv = hp[ii];
                a = fmaf(hv.x, wv.x, fmaf(hv.y, wv.y, fmaf(hv.z, wv.z, fmaf(hv.w, wv.w, a))));
            }
#pragma unroll
            for (int m = 1; m < 32; m <<= 1) a += __shfl_xor(a, m);
            if (sub == 0) s.e8[gp] = a + bo[cnd];
        }
        __syncthreads();
        if (tid == 0) {
            float lv5[TOPKN]; int li5[TOPKN];
#pragma unroll
            for (int q = 0; q < TOPKN; ++q) { lv5[q] = -INFINITY; li5[q] = 0x7fffffff; }
#pragma unroll
            for (int q = 0; q < CAND; ++q) ins5(lv5, li5, s.e8[q], s.c8[q]);
            const int ridx = rix[(t - 1) * BATCH + j];
            int sb = li5[0];
#pragma unroll
            for (int q = 1; q < TOPKN; ++q) if (ridx == q) sb = li5[q];
            astu64(&selFW[j], ((u64)(unsigned)t << 32) | (unsigned)sb);   // payload+flag
        }
    }

    // 3) hg slice (independent of sel — overlaps the sel wait)
    if (tid < 192) {
        const int bb = tid & 31, pp = tid >> 5;
        const int gc = (pp >> 1) * HDIM + 2 * j + (pp & 1);
        const float4* hr = (const float4*)&s.h2s[bb][0];
        const float4* up = (const float4*)(UT + (size_t)gc * DIM);
        float a0 = b_r[gc], a1 = 0.f, a2 = 0.f, a3 = 0.f;
#pragma unroll 4
        for (int i = 0; i < 128; i += 4) {
            const float4 h0 = hr[i],     u0 = up[i];
            const float4 h1 = hr[i + 1], u1 = up[i + 1];
            const float4 h2v = hr[i + 2], u2 = up[i + 2];
            const float4 h3 = hr[i + 3], u3 = up[i + 3];
            a0 = fmaf(h0.x, u0.x, fmaf(h0.y, u0.y, fmaf(h0.z, u0.z, fmaf(h0.w, u0.w, a0))));
            a1 = fmaf(h1.x, u1.x, fmaf(h1.y, u1.y, fmaf(h1.z, u1.z, fmaf(h1.w, u1.w, a1))));
            a2 = fmaf(h2v.x, u2.x, fmaf(h2v.y, u2.y, fmaf(h2v.z, u2.z, fmaf(h2v.w, u2.w, a2))));
            a3 = fmaf(h3.x, u3.x, fmaf(h3.y, u3.y, fmaf(h3.z, u3.z, fmaf(h3.w, u3.w, a3))));
        }
        s.hgv[bb][pp] = (a0 + a1) + (a2 + a3);
    }

    // 4) gather sel (poll selFW: payload embedded, memset to 0 each launch)
    if (t > 0) {
        if (tid < BATCH) {
            u64 v = aldu64(&selFW[tid]);
            long g = 0;
            while ((unsigned)(v >> 32) < (unsigned)t && g < 1000000L) {  // bounded
                __builtin_amdgcn_s_sleep(2);
                v = aldu64(&selFW[tid]);
                ++g;
            }
            s.sel[tid] = (int)(unsigned)v;
        }
    } else if (tid < BATCH) s.sel[tid] = BOSTOK;
    __syncthreads();

    // 5) stage leaky(E[sel]) rows
    {
        const int b = tid >> 3, ch = tid & 7;
        const float4* src = (const float4*)(E + (size_t)s.sel[b] * DIM) + ch * 16;
        float* dst = &s.er[b][ch * 64];
#pragma unroll
        for (int i = 0; i < 16; ++i) {
            float4 v = src[i];
            v.x = v.x > 0.f ? v.x : ALPHA * v.x;
            v.y = v.y > 0.f ? v.y : ALPHA * v.y;
            v.z = v.z > 0.f ? v.z : ALPHA * v.z;
            v.w = v.w > 0.f ? v.w : ALPHA * v.w;
            *(float4*)(dst + 4 * i) = v;
        }
    }
    __syncthreads();

    // 6) xg dots
    if (tid < 192) {
        const int bb = tid & 31, pp = tid >> 5;
        const int gc = (pp >> 1) * HDIM + 2 * j + (pp & 1);
        const float4* er = (const float4*)&s.er[bb][0];
        const float4* wx = (const float4*)(WxT + (size_t)gc * DIM);
        float a0 = b_i[gc], a1 = 0.f, a2 = 0.f, a3 = 0.f;
#pragma unroll 4
        for (int i = 0; i < 128; i += 4) {
            const float4 e0 = er[i],     w0 = wx[i];
            const float4 e1 = er[i + 1], w1 = wx[i + 1];
            const float4 e2 = er[i + 2], w2 = wx[i + 2];
            const float4 e3 = er[i + 3], w3 = wx[i + 3];
            a0 = fmaf(e0.x, w0.x, fmaf(e0.y, w0.y, fmaf(e0.z, w0.z, fmaf(e0.w, w0.w, a0))));
            a1 = fmaf(e1.x, w1.x, fmaf(e1.y, w1.y, fmaf(e1.z, w1.z, fmaf(e1.w, w1.w, a1))));
            a2 = fmaf(e2.x, w2.x, fmaf(e2.y, w2.y, fmaf(e2.z, w2.z, fmaf(e2.w, w2.w, a2))));
            a3 = fmaf(e3.x, w3.x, fmaf(e3.y, w3.y, fmaf(e3.z, w3.z, fmaf(e3.w, w3.w, a3))));
        }
        s.xgs[bb][pp] = (a0 + a1) + (a2 + a3);
    }
    __syncthreads();

    // 7) GRU update -> h2cur (plain stores; kernel boundary publishes)
    if (tid < 64) {
        const int bb = tid >> 1, q = tid & 1, hc = 2 * j + q;
        const float hold = s.h2s[bb][hc];
        const float xz = s.xgs[bb][q], xr = s.xgs[bb][2 + q], xh = s.xgs[bb][4 + q];
        const float hz = s.hgv[bb][q], hr_ = s.hgv[bb][2 + q], hh = s.hgv[bb][4 + q];
        const float z  = 1.f / (1.f + expf(-(xz + hz)));
        const float r  = 1.f / (1.f + expf(-(xr + hr_)));
        const float cd = tanhf(xh + r * hh);
        h2cur[(size_t)bb * HDIM + hc] = z * hold + (1.f - z) * cd;
    }
}

// =====================================================================
// ============= kGemm (primary: no hg; fallback: with hg) =============
// =====================================================================

struct GemmLDS {
    u64      h2r[BATCH][256];     // raw h2 (f32 pairs)   64 KB
    unsigned hbf[BATCH][256];     // bf16-packed, XOR-swz 32 KB
    float pwv[4][BATCH][TOPKN];
    int   pwi[4][BATCH][TOPKN];
};

template <bool WITH_HG>
static __global__ void __launch_bounds__(NTHR, 1)
kGemmT(int t, const unsigned* __restrict__ WoPk, const float* __restrict__ bo,
       const float* __restrict__ UT, const float* __restrict__ b_r,
       const float* __restrict__ h2in, float* __restrict__ out,
       float* __restrict__ hg, u64* __restrict__ pvx)
{
    extern __shared__ char raw[];
    GemmLDS& s = *(GemmLDS*)raw;
    const int j = blockIdx.x, tid = threadIdx.x;
#pragma unroll 4
    for (int q = 0; q < BATCH; ++q) {
        const float2 v = *(const float2*)&h2in[(size_t)q * HDIM + 2 * tid];
        s.h2r[q][tid] = __builtin_bit_cast(u64, v);
        s.hbf[q][tid ^ ((q & 7) << 2)] = f2bf(v.x) | (f2bf(v.y) << 16);  // XOR-swz
    }
    __syncthreads();
    const int w = tid >> 6, l = tid & 63;
    if (j < GEMMBLK) {
        f32x4 acc[2][2];
        acc[0][0] = {0.f,0.f,0.f,0.f}; acc[0][1] = {0.f,0.f,0.f,0.f};
        acc[1][0] = {0.f,0.f,0.f,0.f}; acc[1][1] = {0.f,0.f,0.f,0.f};
        const uint4* wpk = (const uint4*)WoPk;
        const size_t base = (size_t)j * 8192 + l;
        const int r0 = l & 15, r1 = 16 + (l & 15);
        const int ko = (l >> 4) << 2;
        const int swz = (r0 & 7) << 2;
        uint4 vb[8];
#pragma unroll
        for (int pf = 0; pf < 4; ++pf) {           // depth-4 prefetch
            vb[2*pf]   = wpk[base + (size_t)(pf * 8 + 2 * w)     * 64];
            vb[2*pf+1] = wpk[base + (size_t)(pf * 8 + 2 * w + 1) * 64];
        }
#pragma unroll
        for (int ks = 0; ks < 16; ++ks) {
            const int sl2 = (ks & 3) * 2;
            const uint4 b0 = vb[sl2], b1 = vb[sl2 + 1];
            const uint4 a0 = *(const uint4*)&s.hbf[r0][(ks * 16 + ko) ^ swz];
            const uint4 a1 = *(const uint4*)&s.hbf[r1][(ks * 16 + ko) ^ swz];
            if (ks < 12) {
                vb[sl2]     = wpk[base + (size_t)((ks + 4) * 8 + 2 * w)     * 64];
                vb[sl2 + 1] = wpk[base + (size_t)((ks + 4) * 8 + 2 * w + 1) * 64];
            }
            const bf16x8 A0 = __builtin_bit_cast(bf16x8, a0);
            const bf16x8 A1 = __builtin_bit_cast(bf16x8, a1);
            const bf16x8 B0 = __builtin_bit_cast(bf16x8, b0);
            const bf16x8 B1 = __builtin_bit_cast(bf16x8, b1);
            acc[0][0] = __builtin_amdgcn_mfma_f32_16x16x32_bf16(A0, B0, acc[0][0], 0, 0, 0);
            acc[0][1] = __builtin_amdgcn_mfma_f32_16x16x32_bf16(A0, B1, acc[0][1], 0, 0, 0);
            acc[1][0] = __builtin_amdgcn_mfma_f32_16x16x32_bf16(A1, B0, acc[1][0], 0, 0, 0);
            acc[1][1] = __builtin_amdgcn_mfma_f32_16x16x32_bf16(A1, B1, acc[1][1], 0, 0, 0);
        }
        const int c0 = j * CPB + (2 * w) * 16 + (l & 15);
        const int c1 = j * CPB + (2 * w + 1) * 16 + (l & 15);
        const float bo0 = bo[c0], bo1 = bo[c1];
#pragma unroll
        for (int m = 0; m < 2; ++m) {
#pragma unroll
            for (int r = 0; r < 4; ++r) {
                const int b = 16 * m + ((l >> 4) << 2) + r;
                const float v0 = acc[m][0][r] + bo0;
                const float v1 = acc[m][1][r] + bo1;
                __builtin_nontemporal_store(v0, out + ((size_t)b * TSTEPS + t) * VOCAB + c0);
                __builtin_nontemporal_store(v1, out + ((size_t)b * TSTEPS + t) * VOCAB + c1);
                float lv[TOPKN]; int li[TOPKN];
#pragma unroll
                for (int q = 0; q < TOPKN; ++q) { lv[q] = -INFINITY; li[q] = 0x7fffffff; }
                ins5(lv, li, v0, c0);
                ins5(lv, li, v1, c1);
#pragma unroll
                for (int mask = 1; mask < 16; mask <<= 1) {
                    float ov[TOPKN]; int oi[TOPKN];
#pragma unroll
                    for (int q = 0; q < TOPKN; ++q) {
                        ov[q] = __shfl_xor(lv[q], mask);
                        oi[q] = __shfl_xor(li[q], mask);
                    }
#pragma unroll
                    for (int q = 0; q < TOPKN; ++q) ins5(lv, li, ov[q], oi[q]);
                }
                if ((l & 15) == 0) {
#pragma unroll
                    for (int q = 0; q < TOPKN; ++q) { s.pwv[w][b][q] = lv[q]; s.pwi[w][b][q] = li[q]; }
                }
            }
        }
    }
    if (WITH_HG && tid < 192) {   // fallback path only
        const int g  = j * 192 + tid;
        const int bb = j >> 3;
        const int c  = 192 * (j & 7) + tid;
        const float4* hr = (const float4*)&s.h2r[bb][0];
        const float4* up = (const float4*)(UT + (size_t)c * DIM);
        float a0 = b_r[c], a1 = 0.f, a2 = 0.f, a3 = 0.f;
#pragma unroll 4
        for (int i = 0; i < 128; i += 4) {
            const float4 u0 = up[i],     h0 = hr[i];
            const float4 u1 = up[i + 1], h1 = hr[i + 1];
            const float4 u2 = up[i + 2], h2v = hr[i + 2];
            const float4 u3 = up[i + 3], h3 = hr[i + 3];
            a0 = fmaf(h0.x, u0.x, fmaf(h0.y, u0.y, fmaf(h0.z, u0.z, fmaf(h0.w, u0.w, a0))));
            a1 = fmaf(h1.x, u1.x, fmaf(h1.y, u1.y, fmaf(h1.z, u1.z, fmaf(h1.w, u1.w, a1))));
            a2 = fmaf(h2v.x, u2.x, fmaf(h2v.y, u2.y, fmaf(h2v.z, u2.z, fmaf(h2v.w, u2.w, a2))));
            a3 = fmaf(h3.x, u3.x, fmaf(h3.y, u3.y, fmaf(h3.z, u3.z, fmaf(h3.w, u3.w, a3))));
        }
        hg[g] = (a0 + a1) + (a2 + a3);
    }
    __syncthreads();
    if (j < GEMMBLK && tid < BATCH) {
        float lv[TOPKN]; int li[TOPKN];
#pragma unroll
        for (int q = 0; q < TOPKN; ++q) { lv[q] = -INFINITY; li[q] = 0x7fffffff; }
#pragma unroll
        for (int w4 = 0; w4 < 4; ++w4)
#pragma unroll
            for (int q = 0; q < TOPKN; ++q) ins5(lv, li, s.pwv[w4][tid][q], s.pwi[w4][tid][q]);
        const size_t base = ((size_t)tid * GEMMBLK + j) * TOPKN;
#pragma unroll
        for (int q = 0; q < TOPKN; ++q)
            pvx[base + q] = ((u64)__float_as_uint(lv[q]) << 32) | (unsigned)li[q];
    }
}

// =====================================================================
// ============== round-7 fallback kernels (proven) ====================
// =====================================================================

static __global__ void __launch_bounds__(NTHR, 1)
kHg0(const float* __restrict__ ctx, const float* __restrict__ UT,
     const float* __restrict__ b_r, float* __restrict__ hg)
{
    const int j = blockIdx.x, tid = threadIdx.x;
    if (tid < 192) {
        const int g  = j * 192 + tid;
        const int bb = j >> 3;
        const int c  = 192 * (j & 7) + tid;
        const float4* hp = (const float4*)(ctx + (size_t)bb * HDIM);
        const float4* up = (const float4*)(UT + (size_t)c * DIM);
        float a0 = b_r[c], a1 = 0.f, a2 = 0.f, a3 = 0.f;
#pragma unroll 4
        for (int i = 0; i < 128; i += 4) {
            float4 h0 = hp[i],     u0 = up[i];
            float4 h1 = hp[i + 1], u1 = up[i + 1];
            float4 h2v = hp[i + 2], u2 = up[i + 2];
            float4 h3 = hp[i + 3], u3 = up[i + 3];
            a0 = fmaf(h0.x, u0.x, fmaf(h0.y, u0.y, fmaf(h0.z, u0.z, fmaf(h0.w, u0.w, a0))));
            a1 = fmaf(h1.x, u1.x, fmaf(h1.y, u1.y, fmaf(h1.z, u1.z, fmaf(h1.w, u1.w, a1))));
            a2 = fmaf(h2v.x, u2.x, fmaf(h2v.y, u2.y, fmaf(h2v.z, u2.z, fmaf(h2v.w, u2.w, a2))));
            a3 = fmaf(h3.x, u3.x, fmaf(h3.y, u3.y, fmaf(h3.z, u3.z, fmaf(h3.w, u3.w, a3))));
        }
        hg[g] = (a0 + a1) + (a2 + a3);
    }
}

static __global__ void __launch_bounds__(NTHR, 1)
kSel(int t, const float* __restrict__ WoT, const float* __restrict__ bo,
     const int* __restrict__ rix, const float* __restrict__ h2prev,
     const u64* __restrict__ pvx, unsigned* __restrict__ selw)
{
    __shared__ u64   m8[4][CAND];
    __shared__ int   c8[CAND];
    __shared__ float e8[CAND];
    const int b = blockIdx.x, tid = threadIdx.x;
    float lv[TOPKN]; int li[TOPKN];
#pragma unroll
    for (int q = 0; q < TOPKN; ++q) { lv[q] = -INFINITY; li[q] = 0x7fffffff; }
    const u64* pb = pvx + (size_t)b * (GEMMBLK * TOPKN);
    for (int e = tid; e < GEMMBLK * TOPKN; e += NTHR) {
        const u64 v = pb[e];
        ins5(lv, li, __uint_as_float((unsigned)(v >> 32)), (int)(unsigned)v);
    }
    float v8[CAND]; int i8[CAND];
#pragma unroll
    for (int q = 0; q < CAND; ++q) {
        v8[q] = (q < TOPKN) ? lv[q] : -INFINITY;
        i8[q] = (q < TOPKN) ? li[q] : 0x7fffffff;
    }
#pragma unroll
    for (int m = 1; m < 64; m <<= 1) {
#pragma unroll
        for (int q = 0; q < CAND; ++q) {
            const float ov = __shfl_xor(v8[q], m);
            const int   oi = __shfl_xor(i8[q], m);
            ins8(v8, i8, ov, oi);
        }
    }
    if ((tid & 63) == 0) {
#pragma unroll
        for (int q = 0; q < CAND; ++q)
            m8[tid >> 6][q] = ((u64)__float_as_uint(v8[q]) << 32) | (unsigned)i8[q];
    }
    __syncthreads();
    if (tid == 0) {
        float f8[CAND]; int fi[CAND];
#pragma unroll
        for (int q = 0; q < CAND; ++q) { f8[q] = -INFINITY; fi[q] = 0x7fffffff; }
#pragma unroll
        for (int w2 = 0; w2 < 4; ++w2)
#pragma unroll
            for (int q = 0; q < CAND; ++q) {
                const u64 v = m8[w2][q];
                ins8(f8, fi, __uint_as_float((unsigned)(v >> 32)), (int)(unsigned)v);
            }
#pragma unroll
        for (int q = 0; q < CAND; ++q) c8[q] = fi[q];
    }
    __syncthreads();
    {
        const int gp = tid >> 5, sub = tid & 31;
        const int cnd = c8[gp];
        const float4* wp = (const float4*)(WoT + (size_t)cnd * DIM) + sub * 4;
        const float4* hp = (const float4*)(h2prev + (size_t)b * HDIM) + sub * 4;
        float a = 0.f;
#pragma unroll
        for (int ii = 0; ii < 4; ++ii) {
            const float4 wv = wp[ii], hv = hp[ii];
            a = fmaf(hv.x, wv.x, fmaf(hv.y, wv.y, fmaf(hv.z, wv.z, fmaf(hv.w, wv.w, a))));
        }
#pragma unroll
        for (int m = 1; m < 32; m <<= 1) a += __shfl_xor(a, m);
        if (sub == 0) e8[gp] = a + bo[cnd];
    }
    __syncthreads();
    if (tid == 0) {
        float lv5[TOPKN]; int li5[TOPKN];
#pragma unroll
        for (int q = 0; q < TOPKN; ++q) { lv5[q] = -INFINITY; li5[q] = 0x7fffffff; }
#pragma unroll
        for (int q = 0; q < CAND; ++q) ins5(lv5, li5, e8[q], c8[q]);
        const int ridx = rix[(t - 1) * BATCH + b];
        int sb = li5[0];
#pragma unroll
        for (int q = 1; q < TOPKN; ++q) if (ridx == q) sb = li5[q];
        selw[b] = (unsigned)sb;
    }
}

struct GateLDS {
    float er[BATCH][516];
    float xgs[BATCH][6];
    int   sel[BATCH];
};

static __global__ void __launch_bounds__(NTHR, 1)
kGate(int t, const float* __restrict__ E, const float* __restrict__ WxT,
      const float* __restrict__ b_i, const float* __restrict__ ctx,
      const unsigned* __restrict__ selw, const float* __restrict__ hg,
      const float* __restrict__ h2prev, float* __restrict__ h2cur)
{
    extern __shared__ char raw[];
    GateLDS& s = *(GateLDS*)raw;
    const int j = blockIdx.x, tid = threadIdx.x;
    if (tid < BATCH)
        s.sel[tid] = (t == 0) ? BOSTOK : (int)selw[tid];
    __syncthreads();
    {
        const int b = tid >> 3, ch = tid & 7;
        const float4* src = (const float4*)(E + (size_t)s.sel[b] * DIM) + ch * 16;
        float* dst = &s.er[b][ch * 64];
#pragma unroll
        for (int i = 0; i < 16; ++i) {
            float4 v = src[i];
            v.x = v.x > 0.f ? v.x : ALPHA * v.x;
            v.y = v.y > 0.f ? v.y : ALPHA * v.y;
            v.z = v.z > 0.f ? v.z : ALPHA * v.z;
            v.w = v.w > 0.f ? v.w : ALPHA * v.w;
            *(float4*)(dst + 4 * i) = v;
        }
    }
    __syncthreads();
    if (tid < 192) {
        const int bb = tid & 31, pp = tid >> 5;
        const int gc = (pp >> 1) * HDIM + 2 * j + (pp & 1);
        const float4* er = (const float4*)&s.er[bb][0];
        const float4* wx = (const float4*)(WxT + (size_t)gc * DIM);
        float a0 = b_i[gc], a1 = 0.f, a2 = 0.f, a3 = 0.f;
#pragma unroll 4
        for (int i = 0; i < 128; i += 4) {
            const float4 e0 = er[i],     w0 = wx[i];
            const float4 e1 = er[i + 1], w1 = wx[i + 1];
            const float4 e2 = er[i + 2], w2 = wx[i + 2];
            const float4 e3 = er[i + 3], w3 = wx[i + 3];
            a0 = fmaf(e0.x, w0.x, fmaf(e0.y, w0.y, fmaf(e0.z, w0.z, fmaf(e0.w, w0.w, a0))));
            a1 = fmaf(e1.x, w1.x, fmaf(e1.y, w1.y, fmaf(e1.z, w1.z, fmaf(e1.w, w1.w, a1))));
            a2 = fmaf(e2.x, w2.x, fmaf(e2.y, w2.y, fmaf(e2.z, w2.z, fmaf(e2.w, w2.w, a2))));
            a3 = fmaf(e3.x, w3.x, fmaf(e3.y, w3.y, fmaf(e3.z, w3.z, fmaf(e3.w, w3.w, a3))));
        }
        s.xgs[bb][pp] = (a0 + a1) + (a2 + a3);
    }
    __syncthreads();
    if (tid < 64) {
        const int bb = tid >> 1, q = tid & 1, hc = 2 * j + q;
        const float hold = (t == 0) ? ctx[(size_t)bb * HDIM + hc]
                                    : h2prev[(size_t)bb * HDIM + hc];
        const float xz = s.xgs[bb][q], xr = s.xgs[bb][2 + q], xh = s.xgs[bb][4 + q];
        const float hz  = hg[(size_t)bb * G3H + hc];
        const float hr_ = hg[(size_t)bb * G3H + HDIM + hc];
        const float hh  = hg[(size_t)bb * G3H + 2 * HDIM + hc];
        const float z  = 1.f / (1.f + expf(-(xz + hz)));
        const float r  = 1.f / (1.f + expf(-(xr + hr_)));
        const float cd = tanhf(xh + r * hh);
        h2cur[(size_t)bb * HDIM + hc] = z * hold + (1.f - z) * cd;
    }
}

// =====================================================================
extern "C" void kernel_launch(void* const* d_in, const int* in_sizes, int n_in,
                              void* d_out, int out_size, void* d_ws, size_t ws_size,
                              hipStream_t stream) {
    (void)in_sizes; (void)n_in; (void)out_size;
    const float* E   = (const float*)d_in[0];
    const float* Wx  = (const float*)d_in[1];
    const float* U   = (const float*)d_in[2];
    const float* b_i = (const float*)d_in[3];
    const float* b_r = (const float*)d_in[4];
    const float* Wo  = (const float*)d_in[5];
    const float* bo  = (const float*)d_in[6];
    const float* ctx = (const float*)d_in[7];
    const int*   rix = (const int*)d_in[8];
    float* out = (float*)d_out;

    int dev = 0;
    (void)hipGetDevice(&dev);
    int numCU = 0;
    (void)hipDeviceGetAttribute(&numCU, hipDeviceAttributeMultiprocessorCount, dev);

    // ---- ws layout (bytes, 8B aligned; proven footprint) ----
    const size_t oWoPk = 0;            // 512*32000*2      = 32,768,000
    const size_t oWoT  = 32768000;     // 32000*512*4      = 65,536,000
    const size_t oUT   = 98304000;     // 1536*512*4       =  3,145,728
    const size_t oWxT  = 101449728;    // 1536*512*4       =  3,145,728
    const size_t oH2X  = 104595456;    // 2*32*512*4       =    131,072
    const size_t oHG   = 104726528;    // 32*1536*4        =    196,608
    const size_t oPVX  = 104923136;    // 32*250*5*8       =    320,000
    const size_t oBAR  = 105243136;    // selFW[32] u64 (256 B) + selw[32] u32
    const size_t need  = 105245312;

    if (ws_size < need) return;   // cannot run (ws has always been >= this)

    char* w = (char*)d_ws;
    unsigned* WoPk = (unsigned*)(w + oWoPk);
    float* WoT  = (float*)(w + oWoT);
    float* UT   = (float*)(w + oUT);
    float* WxT  = (float*)(w + oWxT);
    float* h2f  = (float*)(w + oH2X);
    float* hg   = (float*)(w + oHG);
    u64*   pvx  = (u64*)(w + oPVX);
    u64*      selFW = (u64*)(w + oBAR);
    unsigned* selw  = (unsigned*)(w + oBAR + 1024);

    const int GS_LDS   = (int)sizeof(GSLDS);
    const int GEMM_LDS = (int)sizeof(GemmLDS);
    const int GATE_LDS = (int)sizeof(GateLDS);
    (void)hipFuncSetAttribute((const void*)kGateSel,
                              hipFuncAttributeMaxDynamicSharedMemorySize, GS_LDS);
    (void)hipFuncSetAttribute((const void*)kGemmT<false>,
                              hipFuncAttributeMaxDynamicSharedMemorySize, GEMM_LDS);
    (void)hipFuncSetAttribute((const void*)kGemmT<true>,
                              hipFuncAttributeMaxDynamicSharedMemorySize, GEMM_LDS);
    (void)hipFuncSetAttribute((const void*)kGate,
                              hipFuncAttributeMaxDynamicSharedMemorySize, GATE_LDS);

    int maxBlk = 0;
    (void)hipOccupancyMaxActiveBlocksPerMultiprocessor(&maxBlk, kGateSel, NTHR, GS_LDS);
    const bool primary = (maxBlk >= 1) && (numCU >= NBLK);

    kProlog<<<dim3(NBLK), dim3(NTHR), 0, stream>>>(Wo, U, Wx, WoPk, WoT, UT, WxT);

    if (primary) {
        // 2 kernels/step: kGateSel (SEL+hg+gates) -> kGemm (logits+partials)
        (void)hipMemsetAsync((void*)selFW, 0, 256, stream);
        for (int t = 0; t < TSTEPS; ++t) {
            float*       h2cur  = h2f + ((t & 1) ^ 1) * (BATCH * HDIM);
            const float* h2prev = h2f + (t & 1) * (BATCH * HDIM);
            kGateSel<<<dim3(NBLK), dim3(NTHR), GS_LDS, stream>>>(
                t, E, WxT, UT, b_i, b_r, WoT, bo, rix, ctx, h2prev, h2cur, pvx, selFW);
            kGemmT<false><<<dim3(NBLK), dim3(NTHR), GEMM_LDS, stream>>>(
                t, WoPk, bo, UT, b_r, h2cur, out, hg, pvx);
        }
    } else {
        // proven round-7 3-kernel path
        kHg0<<<dim3(NBLK), dim3(NTHR), 0, stream>>>(ctx, UT, b_r, hg);
        for (int t = 0; t < TSTEPS; ++t) {
            float*       h2cur  = h2f + ((t & 1) ^ 1) * (BATCH * HDIM);
            const float* h2prev = h2f + (t & 1) * (BATCH * HDIM);
            if (t > 0)
                kSel<<<dim3(BATCH), dim3(NTHR), 0, stream>>>(t, WoT, bo, rix,
                                                             h2prev, pvx, selw);
            kGate<<<dim3(NBLK), dim3(NTHR), GATE_LDS, stream>>>(t, E, WxT, b_i, ctx,
                                                                selw, hg, h2prev, h2cur);
            kGemmT<true><<<dim3(NBLK), dim3(NTHR), GEMM_LDS, stream>>>(
                t, WoPk, bo, UT, b_r, h2cur, out, hg, pvx);
        }
    }
}

// Round 10
// 14256.555 us; speedup vs baseline: 1.0507x; 1.0211x over previous
//
#include <hip/hip_runtime.h>

#define VOCAB   32000
#define DIM     512
#define HDIM    512
#define BATCH   32
#define TSTEPS  128
#define TOPKN   5
#define CAND    8
#define BOSTOK  1
#define ALPHA   0.2f
#define G3H     1536

#define NBLK    256
#define NTHR    256
#define GEMMBLK 250
#define CPB     128

typedef unsigned long long u64;
typedef __bf16 bf16x8 __attribute__((ext_vector_type(8)));
typedef float  f32x4  __attribute__((ext_vector_type(4)));

// ---------------- shared helpers ----------------
__device__ __forceinline__ bool better(float v1, int i1, float v2, int i2) {
    return (v1 > v2) || (v1 == v2 && i1 < i2);   // value desc, index asc
}

__device__ __forceinline__ void ins5(float (&lv)[TOPKN], int (&li)[TOPKN], float v, int i) {
    if (better(v, i, lv[4], li[4])) {
        lv[4] = v; li[4] = i;
#pragma unroll
        for (int q = 4; q > 0; --q) {
            if (better(lv[q], li[q], lv[q - 1], li[q - 1])) {
                float tv = lv[q]; lv[q] = lv[q - 1]; lv[q - 1] = tv;
                int   ti = li[q]; li[q] = li[q - 1]; li[q - 1] = ti;
            }
        }
    }
}

__device__ __forceinline__ void ins8(float (&lv)[CAND], int (&li)[CAND], float v, int i) {
    if (better(v, i, lv[CAND - 1], li[CAND - 1])) {
        lv[CAND - 1] = v; li[CAND - 1] = i;
#pragma unroll
        for (int q = CAND - 1; q > 0; --q) {
            if (better(lv[q], li[q], lv[q - 1], li[q - 1])) {
                float tv = lv[q]; lv[q] = lv[q - 1]; lv[q - 1] = tv;
                int   ti = li[q]; li[q] = li[q - 1]; li[q - 1] = ti;
            }
        }
    }
}

__device__ __forceinline__ unsigned f2bf(float f) {   // f32 -> bf16 RNE
    unsigned u = __float_as_uint(f);
    return (u + 0x7FFFu + ((u >> 16) & 1u)) >> 16;
}

// agent-scope atomics — ONLY for the intra-kernel selFW edge
__device__ __forceinline__ u64 aldu64(const u64* p) {
    return __hip_atomic_load(p, __ATOMIC_RELAXED, __HIP_MEMORY_SCOPE_AGENT);
}
__device__ __forceinline__ void astu64(u64* p, u64 v) {
    __hip_atomic_store(p, v, __ATOMIC_RELAXED, __HIP_MEMORY_SCOPE_AGENT);
}

// ---------------- prologue: WoPk / WoT / UT / WxT (proven r3-r9) ----------------
static __global__ void __launch_bounds__(NTHR, 1)
kProlog(const float* __restrict__ Wo, const float* __restrict__ U,
        const float* __restrict__ Wx,
        unsigned* __restrict__ WoPk, float* __restrict__ WoT,
        float* __restrict__ UT, float* __restrict__ WxT)
{
    __shared__ float tile[64][129];
    const int j = blockIdx.x, tid = threadIdx.x;
    for (int i = tid; i < 6 * DIM; i += NTHR) {
        const int rr = i >> 9, k = i & 511;
        const int gc = (rr >> 1) * HDIM + 2 * j + (rr & 1);
        UT[(size_t)gc * DIM + k]  = U[(size_t)k * G3H + gc];
        WxT[(size_t)gc * DIM + k] = Wx[(size_t)k * G3H + gc];
    }
    if (j < GEMMBLK) {
        for (int chunk = 0; chunk < 8; ++chunk) {
            const int k0 = chunk * 64;
            __syncthreads();
#pragma unroll
            for (int it = 0; it < 8; ++it) {
                const int idx = tid + it * NTHR;
                const int kk = idx >> 5, c4 = (idx & 31) << 2;
                const float4 v = *(const float4*)(Wo + (size_t)(k0 + kk) * VOCAB + j * CPB + c4);
                tile[kk][c4] = v.x; tile[kk][c4 + 1] = v.y;
                tile[kk][c4 + 2] = v.z; tile[kk][c4 + 3] = v.w;
            }
            __syncthreads();
            {
                const int kh = tid >> 7, c = tid & 127;
                float* dst = WoT + ((size_t)j * CPB + c) * DIM + k0 + kh * 32;
#pragma unroll
                for (int kk = 0; kk < 32; ++kk) dst[kk] = tile[kh * 32 + kk][c];
            }
#pragma unroll
            for (int uu = 0; uu < 4; ++uu) {
                const int u = tid + uu * NTHR;
                const int kss = u >> 9, nt = (u >> 6) & 7, ll = u & 63;
                const int kb = kss * 32 + ((ll >> 4) << 3);
                const int c  = nt * 16 + (ll & 15);
                unsigned d[4];
#pragma unroll
                for (int e2 = 0; e2 < 4; ++e2) {
                    const unsigned lo = f2bf(tile[kb + 2 * e2][c]);
                    const unsigned hi = f2bf(tile[kb + 2 * e2 + 1][c]);
                    d[e2] = lo | (hi << 16);
                }
                const int ksg = chunk * 2 + kss;
                uint4* dst = (uint4*)WoPk + ((((size_t)j * 16 + ksg) * 8 + nt) * 64 + ll);
                *dst = *(const uint4*)d;
            }
        }
    }
}

// =====================================================================
// ======== primary: kGateSel (SEL folded into GATE, 1 kernel) =========
// =====================================================================

struct GSLDS {
    float h2s[BATCH][516];   // staged h2_{t-1} (66 KB)
    float er[BATCH][516];    // staged leaky(E[sel]) (66 KB)
    float xgs[BATCH][6];
    float hgv[BATCH][6];
    int   sel[BATCH];
    u64   m8[4][CAND];
    int   c8[CAND];
    float e8[CAND];
};                           // ~134 KB dynamic

static __global__ void __launch_bounds__(NTHR, 1)
kGateSel(int t, const float* __restrict__ E, const float* __restrict__ WxT,
         const float* __restrict__ UT, const float* __restrict__ b_i,
         const float* __restrict__ b_r, const float* __restrict__ WoT,
         const float* __restrict__ bo, const int* __restrict__ rix,
         const float* __restrict__ ctx, const float* __restrict__ h2prev,
         float* __restrict__ h2cur, const u64* __restrict__ pvx,
         u64* __restrict__ selFW)
{
    extern __shared__ char raw[];
    GSLDS& s = *(GSLDS*)raw;
    const int j = blockIdx.x, tid = threadIdx.x;

    // 1) stage h2_{t-1} (or ctx) -> LDS, coalesced (16 loads in flight)
    const float* hsrc = (t == 0) ? ctx : h2prev;
#pragma unroll
    for (int it = 0; it < 16; ++it) {
        const int i = tid + it * NTHR;          // 0..4095 float4
        const int r = i >> 7, c4 = i & 127;
        *(float4*)&s.h2s[r][c4 * 4] = ((const float4*)hsrc)[i];
    }
    __syncthreads();

    // 2) SEL (blocks 0..31, t>0): merge partials -> top8 -> exact rescore -> publish
    if (t > 0 && j < BATCH) {
        float lv[TOPKN]; int li[TOPKN];
#pragma unroll
        for (int q = 0; q < TOPKN; ++q) { lv[q] = -INFINITY; li[q] = 0x7fffffff; }
        const u64* pb = pvx + (size_t)j * (GEMMBLK * TOPKN);
        // burst all 5 partial loads BEFORE any sorting (MLP)
        const u64 SENT = 0xFF8000007FFFFFFFULL;   // {-inf | INT_MAX}
        const u64 v0 = pb[tid];
        const u64 v1 = pb[tid + 256];
        const u64 v2 = pb[tid + 512];
        const u64 v3 = pb[tid + 768];
        const u64 v4 = (tid < GEMMBLK * TOPKN - 1024) ? pb[tid + 1024] : SENT;
        ins5(lv, li, __uint_as_float((unsigned)(v0 >> 32)), (int)(unsigned)v0);
        ins5(lv, li, __uint_as_float((unsigned)(v1 >> 32)), (int)(unsigned)v1);
        ins5(lv, li, __uint_as_float((unsigned)(v2 >> 32)), (int)(unsigned)v2);
        ins5(lv, li, __uint_as_float((unsigned)(v3 >> 32)), (int)(unsigned)v3);
        ins5(lv, li, __uint_as_float((unsigned)(v4 >> 32)), (int)(unsigned)v4);
        float v8[CAND]; int i8[CAND];
#pragma unroll
        for (int q = 0; q < CAND; ++q) {
            v8[q] = (q < TOPKN) ? lv[q] : -INFINITY;
            i8[q] = (q < TOPKN) ? li[q] : 0x7fffffff;
        }
#pragma unroll
        for (int m = 1; m < 64; m <<= 1) {
#pragma unroll
            for (int q = 0; q < CAND; ++q) {
                const float ov = __shfl_xor(v8[q], m);
                const int   oi = __shfl_xor(i8[q], m);
                ins8(v8, i8, ov, oi);
            }
        }
        if ((tid & 63) == 0) {
#pragma unroll
            for (int q = 0; q < CAND; ++q)
                s.m8[tid >> 6][q] = ((u64)__float_as_uint(v8[q]) << 32) | (unsigned)i8[q];
        }
        __syncthreads();
        if (tid == 0) {
            float f8[CAND]; int fi[CAND];
#pragma unroll
            for (int q = 0; q < CAND; ++q) { f8[q] = -INFINITY; fi[q] = 0x7fffffff; }
#pragma unroll
            for (int w2 = 0; w2 < 4; ++w2)
#pragma unroll
                for (int q = 0; q < CAND; ++q) {
                    const u64 v = s.m8[w2][q];
                    ins8(f8, fi, __uint_as_float((unsigned)(v >> 32)), (int)(unsigned)v);
                }
#pragma unroll
            for (int q = 0; q < CAND; ++q) s.c8[q] = fi[q];
        }
        __syncthreads();
        {   // exact f32 rescore: 8 groups x 32 lanes; h2 from LDS, WoT coalesced
            const int gp = tid >> 5, sub = tid & 31;
            const int cnd = s.c8[gp];
            const float4* wp = (const float4*)(WoT + (size_t)cnd * DIM) + sub * 4;
            const float4* hp = (const float4*)&s.h2s[j][sub * 16];
            const float4 w0 = wp[0], w1 = wp[1], w2 = wp[2], w3 = wp[3];
            const float4 h0 = hp[0], h1 = hp[1], h2v = hp[2], h3 = hp[3];
            float a = 0.f;
            a = fmaf(h0.x, w0.x, fmaf(h0.y, w0.y, fmaf(h0.z, w0.z, fmaf(h0.w, w0.w, a))));
            a = fmaf(h1.x, w1.x, fmaf(h1.y, w1.y, fmaf(h1.z, w1.z, fmaf(h1.w, w1.w, a))));
            a = fmaf(h2v.x, w2.x, fmaf(h2v.y, w2.y, fmaf(h2v.z, w2.z, fmaf(h2v.w, w2.w, a))));
            a = fmaf(h3.x, w3.x, fmaf(h3.y, w3.y, fmaf(h3.z, w3.z, fmaf(h3.w, w3.w, a))));
#pragma unroll
            for (int m = 1; m < 32; m <<= 1) a += __shfl_xor(a, m);
            if (sub == 0) s.e8[gp] = a + bo[cnd];
        }
        __syncthreads();
        if (tid == 0) {
            float lv5[TOPKN]; int li5[TOPKN];
#pragma unroll
            for (int q = 0; q < TOPKN; ++q) { lv5[q] = -INFINITY; li5[q] = 0x7fffffff; }
#pragma unroll
            for (int q = 0; q < CAND; ++q) ins5(lv5, li5, s.e8[q], s.c8[q]);
            const int ridx = rix[(t - 1) * BATCH + j];
            int sb = li5[0];
#pragma unroll
            for (int q = 1; q < TOPKN; ++q) if (ridx == q) sb = li5[q];
            astu64(&selFW[j], ((u64)(unsigned)t << 32) | (unsigned)sb);   // payload+flag
        }
    }

    // 3) hg slice (independent of sel — overlaps the sel wait), 8-deep MLP
    if (tid < 192) {
        const int bb = tid & 31, pp = tid >> 5;
        const int gc = (pp >> 1) * HDIM + 2 * j + (pp & 1);
        const float4* hr = (const float4*)&s.h2s[bb][0];
        const float4* up = (const float4*)(UT + (size_t)gc * DIM);
        float acc[8];
        acc[0] = b_r[gc];
#pragma unroll
        for (int q = 1; q < 8; ++q) acc[q] = 0.f;
        for (int i = 0; i < 128; i += 8) {
#pragma unroll
            for (int u8 = 0; u8 < 8; ++u8) {
                const float4 h = hr[i + u8], uu = up[i + u8];
                acc[u8] = fmaf(h.x, uu.x, fmaf(h.y, uu.y, fmaf(h.z, uu.z, fmaf(h.w, uu.w, acc[u8]))));
            }
        }
        s.hgv[bb][pp] = ((acc[0] + acc[1]) + (acc[2] + acc[3]))
                      + ((acc[4] + acc[5]) + (acc[6] + acc[7]));
    }

    // 4) gather sel (poll selFW: payload embedded, memset to 0 each launch)
    if (t > 0) {
        if (tid < BATCH) {
            u64 v = aldu64(&selFW[tid]);
            long g = 0;
            while ((unsigned)(v >> 32) < (unsigned)t && g < 1000000L) {  // bounded
                __builtin_amdgcn_s_sleep(2);
                v = aldu64(&selFW[tid]);
                ++g;
            }
            s.sel[tid] = (int)(unsigned)v;
        }
    } else if (tid < BATCH) s.sel[tid] = BOSTOK;
    __syncthreads();

    // 5) stage leaky(E[sel]) rows
    {
        const int b = tid >> 3, ch = tid & 7;
        const float4* src = (const float4*)(E + (size_t)s.sel[b] * DIM) + ch * 16;
        float* dst = &s.er[b][ch * 64];
#pragma unroll
        for (int i = 0; i < 16; ++i) {
            float4 v = src[i];
            v.x = v.x > 0.f ? v.x : ALPHA * v.x;
            v.y = v.y > 0.f ? v.y : ALPHA * v.y;
            v.z = v.z > 0.f ? v.z : ALPHA * v.z;
            v.w = v.w > 0.f ? v.w : ALPHA * v.w;
            *(float4*)(dst + 4 * i) = v;
        }
    }
    __syncthreads();

    // 6) xg dots, 8-deep MLP
    if (tid < 192) {
        const int bb = tid & 31, pp = tid >> 5;
        const int gc = (pp >> 1) * HDIM + 2 * j + (pp & 1);
        const float4* er = (const float4*)&s.er[bb][0];
        const float4* wx = (const float4*)(WxT + (size_t)gc * DIM);
        float acc[8];
        acc[0] = b_i[gc];
#pragma unroll
        for (int q = 1; q < 8; ++q) acc[q] = 0.f;
        for (int i = 0; i < 128; i += 8) {
#pragma unroll
            for (int u8 = 0; u8 < 8; ++u8) {
                const float4 e = er[i + u8], ww = wx[i + u8];
                acc[u8] = fmaf(e.x, ww.x, fmaf(e.y, ww.y, fmaf(e.z, ww.z, fmaf(e.w, ww.w, acc[u8]))));
            }
        }
        s.xgs[bb][pp] = ((acc[0] + acc[1]) + (acc[2] + acc[3]))
                      + ((acc[4] + acc[5]) + (acc[6] + acc[7]));
    }
    __syncthreads();

    // 7) GRU update -> h2cur (plain stores; kernel boundary publishes)
    if (tid < 64) {
        const int bb = tid >> 1, q = tid & 1, hc = 2 * j + q;
        const float hold = s.h2s[bb][hc];
        const float xz = s.xgs[bb][q], xr = s.xgs[bb][2 + q], xh = s.xgs[bb][4 + q];
        const float hz = s.hgv[bb][q], hr_ = s.hgv[bb][2 + q], hh = s.hgv[bb][4 + q];
        const float z  = 1.f / (1.f + expf(-(xz + hz)));
        const float r  = 1.f / (1.f + expf(-(xr + hr_)));
        const float cd = tanhf(xh + r * hh);
        h2cur[(size_t)bb * HDIM + hc] = z * hold + (1.f - z) * cd;
    }
}

// =====================================================================
// ============= kGemm (primary: no hg; fallback: with hg) =============
// =====================================================================

struct GemmLDS {
    u64      h2r[BATCH][256];     // raw h2 (fallback only)
    unsigned hbf[BATCH][256];     // bf16-packed, XOR-swz 32 KB
    float pwv[4][BATCH][TOPKN];
    int   pwi[4][BATCH][TOPKN];
};

template <bool WITH_HG>
static __global__ void __launch_bounds__(NTHR, 1)
kGemmT(int t, const unsigned* __restrict__ WoPk, const float* __restrict__ bo,
       const float* __restrict__ UT, const float* __restrict__ b_r,
       const float* __restrict__ h2in, float* __restrict__ out,
       float* __restrict__ hg, u64* __restrict__ pvx)
{
    extern __shared__ char raw[];
    GemmLDS& s = *(GemmLDS*)raw;
    const int j = blockIdx.x, tid = threadIdx.x;
    const int w = tid >> 6, l = tid & 63;
    const bool gemmer = (j < GEMMBLK);

    // ---- burst-issue ALL 32 WoPk uint4 loads (latency hides under staging) ----
    const uint4* wpk = (const uint4*)WoPk;
    const size_t base = (size_t)j * 8192 + l;
    uint4 vb[32];
    if (gemmer) {
#pragma unroll
        for (int ks = 0; ks < 16; ++ks) {
            vb[2 * ks]     = wpk[base + (size_t)(ks * 8 + 2 * w)     * 64];
            vb[2 * ks + 1] = wpk[base + (size_t)(ks * 8 + 2 * w + 1) * 64];
        }
    }

    // ---- stage h2 -> LDS (8 loads in flight; overlaps WoPk burst) ----
#pragma unroll 8
    for (int q = 0; q < BATCH; ++q) {
        const float2 v = *(const float2*)&h2in[(size_t)q * HDIM + 2 * tid];
        if (WITH_HG) s.h2r[q][tid] = __builtin_bit_cast(u64, v);
        s.hbf[q][tid ^ ((q & 7) << 2)] = f2bf(v.x) | (f2bf(v.y) << 16);  // XOR-swz
    }
    __syncthreads();

    if (gemmer) {
        f32x4 acc[2][2];
        acc[0][0] = {0.f,0.f,0.f,0.f}; acc[0][1] = {0.f,0.f,0.f,0.f};
        acc[1][0] = {0.f,0.f,0.f,0.f}; acc[1][1] = {0.f,0.f,0.f,0.f};
        const int r0 = l & 15, r1 = 16 + (l & 15);
        const int ko = (l >> 4) << 2;
        const int swz = (r0 & 7) << 2;
#pragma unroll
        for (int ks = 0; ks < 16; ++ks) {
            const uint4 b0 = vb[2 * ks], b1 = vb[2 * ks + 1];
            const uint4 a0 = *(const uint4*)&s.hbf[r0][(ks * 16 + ko) ^ swz];
            const uint4 a1 = *(const uint4*)&s.hbf[r1][(ks * 16 + ko) ^ swz];
            const bf16x8 A0 = __builtin_bit_cast(bf16x8, a0);
            const bf16x8 A1 = __builtin_bit_cast(bf16x8, a1);
            const bf16x8 B0 = __builtin_bit_cast(bf16x8, b0);
            const bf16x8 B1 = __builtin_bit_cast(bf16x8, b1);
            acc[0][0] = __builtin_amdgcn_mfma_f32_16x16x32_bf16(A0, B0, acc[0][0], 0, 0, 0);
            acc[0][1] = __builtin_amdgcn_mfma_f32_16x16x32_bf16(A0, B1, acc[0][1], 0, 0, 0);
            acc[1][0] = __builtin_amdgcn_mfma_f32_16x16x32_bf16(A1, B0, acc[1][0], 0, 0, 0);
            acc[1][1] = __builtin_amdgcn_mfma_f32_16x16x32_bf16(A1, B1, acc[1][1], 0, 0, 0);
        }
        const int c0 = j * CPB + (2 * w) * 16 + (l & 15);
        const int c1 = j * CPB + (2 * w + 1) * 16 + (l & 15);
        const float bo0 = bo[c0], bo1 = bo[c1];
#pragma unroll
        for (int m = 0; m < 2; ++m) {
#pragma unroll
            for (int r = 0; r < 4; ++r) {
                const int b = 16 * m + ((l >> 4) << 2) + r;
                const float v0 = acc[m][0][r] + bo0;
                const float v1 = acc[m][1][r] + bo1;
                __builtin_nontemporal_store(v0, out + ((size_t)b * TSTEPS + t) * VOCAB + c0);
                __builtin_nontemporal_store(v1, out + ((size_t)b * TSTEPS + t) * VOCAB + c1);
                float lv[TOPKN]; int li[TOPKN];
#pragma unroll
                for (int q = 0; q < TOPKN; ++q) { lv[q] = -INFINITY; li[q] = 0x7fffffff; }
                ins5(lv, li, v0, c0);
                ins5(lv, li, v1, c1);
#pragma unroll
                for (int mask = 1; mask < 16; mask <<= 1) {
                    float ov[TOPKN]; int oi[TOPKN];
#pragma unroll
                    for (int q = 0; q < TOPKN; ++q) {
                        ov[q] = __shfl_xor(lv[q], mask);
                        oi[q] = __shfl_xor(li[q], mask);
                    }
#pragma unroll
                    for (int q = 0; q < TOPKN; ++q) ins5(lv, li, ov[q], oi[q]);
                }
                if ((l & 15) == 0) {
#pragma unroll
                    for (int q = 0; q < TOPKN; ++q) { s.pwv[w][b][q] = lv[q]; s.pwi[w][b][q] = li[q]; }
                }
            }
        }
    }
    if (WITH_HG && tid < 192) {   // fallback path only
        const int g  = j * 192 + tid;
        const int bb = j >> 3;
        const int c  = 192 * (j & 7) + tid;
        const float4* hr = (const float4*)&s.h2r[bb][0];
        const float4* up = (const float4*)(UT + (size_t)c * DIM);
        float a0 = b_r[c], a1 = 0.f, a2 = 0.f, a3 = 0.f;
#pragma unroll 4
        for (int i = 0; i < 128; i += 4) {
            const float4 u0 = up[i],     h0 = hr[i];
            const float4 u1 = up[i + 1], h1 = hr[i + 1];
            const float4 u2 = up[i + 2], h2v = hr[i + 2];
            const float4 u3 = up[i + 3], h3 = hr[i + 3];
            a0 = fmaf(h0.x, u0.x, fmaf(h0.y, u0.y, fmaf(h0.z, u0.z, fmaf(h0.w, u0.w, a0))));
            a1 = fmaf(h1.x, u1.x, fmaf(h1.y, u1.y, fmaf(h1.z, u1.z, fmaf(h1.w, u1.w, a1))));
            a2 = fmaf(h2v.x, u2.x, fmaf(h2v.y, u2.y, fmaf(h2v.z, u2.z, fmaf(h2v.w, u2.w, a2))));
            a3 = fmaf(h3.x, u3.x, fmaf(h3.y, u3.y, fmaf(h3.z, u3.z, fmaf(h3.w, u3.w, a3))));
        }
        hg[g] = (a0 + a1) + (a2 + a3);
    }
    __syncthreads();
    if (gemmer && tid < BATCH) {
        float lv[TOPKN]; int li[TOPKN];
#pragma unroll
        for (int q = 0; q < TOPKN; ++q) { lv[q] = -INFINITY; li[q] = 0x7fffffff; }
#pragma unroll
        for (int w4 = 0; w4 < 4; ++w4)
#pragma unroll
            for (int q = 0; q < TOPKN; ++q) ins5(lv, li, s.pwv[w4][tid][q], s.pwi[w4][tid][q]);
        const size_t pbx = ((size_t)tid * GEMMBLK + j) * TOPKN;
#pragma unroll
        for (int q = 0; q < TOPKN; ++q)
            pvx[pbx + q] = ((u64)__float_as_uint(lv[q]) << 32) | (unsigned)li[q];
    }
}

// =====================================================================
// ============== round-7 fallback kernels (proven) ====================
// =====================================================================

static __global__ void __launch_bounds__(NTHR, 1)
kHg0(const float* __restrict__ ctx, const float* __restrict__ UT,
     const float* __restrict__ b_r, float* __restrict__ hg)
{
    const int j = blockIdx.x, tid = threadIdx.x;
    if (tid < 192) {
        const int g  = j * 192 + tid;
        const int bb = j >> 3;
        const int c  = 192 * (j & 7) + tid;
        const float4* hp = (const float4*)(ctx + (size_t)bb * HDIM);
        const float4* up = (const float4*)(UT + (size_t)c * DIM);
        float a0 = b_r[c], a1 = 0.f, a2 = 0.f, a3 = 0.f;
#pragma unroll 4
        for (int i = 0; i < 128; i += 4) {
            float4 h0 = hp[i],     u0 = up[i];
            float4 h1 = hp[i + 1], u1 = up[i + 1];
            float4 h2v = hp[i + 2], u2 = up[i + 2];
            float4 h3 = hp[i + 3], u3 = up[i + 3];
            a0 = fmaf(h0.x, u0.x, fmaf(h0.y, u0.y, fmaf(h0.z, u0.z, fmaf(h0.w, u0.w, a0))));
            a1 = fmaf(h1.x, u1.x, fmaf(h1.y, u1.y, fmaf(h1.z, u1.z, fmaf(h1.w, u1.w, a1))));
            a2 = fmaf(h2v.x, u2.x, fmaf(h2v.y, u2.y, fmaf(h2v.z, u2.z, fmaf(h2v.w, u2.w, a2))));
            a3 = fmaf(h3.x, u3.x, fmaf(h3.y, u3.y, fmaf(h3.z, u3.z, fmaf(h3.w, u3.w, a3))));
        }
        hg[g] = (a0 + a1) + (a2 + a3);
    }
}

static __global__ void __launch_bounds__(NTHR, 1)
kSel(int t, const float* __restrict__ WoT, const float* __restrict__ bo,
     const int* __restrict__ rix, const float* __restrict__ h2prev,
     const u64* __restrict__ pvx, unsigned* __restrict__ selw)
{
    __shared__ u64   m8[4][CAND];
    __shared__ int   c8[CAND];
    __shared__ float e8[CAND];
    const int b = blockIdx.x, tid = threadIdx.x;
    float lv[TOPKN]; int li[TOPKN];
#pragma unroll
    for (int q = 0; q < TOPKN; ++q) { lv[q] = -INFINITY; li[q] = 0x7fffffff; }
    const u64* pb = pvx + (size_t)b * (GEMMBLK * TOPKN);
    for (int e = tid; e < GEMMBLK * TOPKN; e += NTHR) {
        const u64 v = pb[e];
        ins5(lv, li, __uint_as_float((unsigned)(v >> 32)), (int)(unsigned)v);
    }
    float v8[CAND]; int i8[CAND];
#pragma unroll
    for (int q = 0; q < CAND; ++q) {
        v8[q] = (q < TOPKN) ? lv[q] : -INFINITY;
        i8[q] = (q < TOPKN) ? li[q] : 0x7fffffff;
    }
#pragma unroll
    for (int m = 1; m < 64; m <<= 1) {
#pragma unroll
        for (int q = 0; q < CAND; ++q) {
            const float ov = __shfl_xor(v8[q], m);
            const int   oi = __shfl_xor(i8[q], m);
            ins8(v8, i8, ov, oi);
        }
    }
    if ((tid & 63) == 0) {
#pragma unroll
        for (int q = 0; q < CAND; ++q)
            m8[tid >> 6][q] = ((u64)__float_as_uint(v8[q]) << 32) | (unsigned)i8[q];
    }
    __syncthreads();
    if (tid == 0) {
        float f8[CAND]; int fi[CAND];
#pragma unroll
        for (int q = 0; q < CAND; ++q) { f8[q] = -INFINITY; fi[q] = 0x7fffffff; }
#pragma unroll
        for (int w2 = 0; w2 < 4; ++w2)
#pragma unroll
            for (int q = 0; q < CAND; ++q) {
                const u64 v = m8[w2][q];
                ins8(f8, fi, __uint_as_float((unsigned)(v >> 32)), (int)(unsigned)v);
            }
#pragma unroll
        for (int q = 0; q < CAND; ++q) c8[q] = fi[q];
    }
    __syncthreads();
    {
        const int gp = tid >> 5, sub = tid & 31;
        const int cnd = c8[gp];
        const float4* wp = (const float4*)(WoT + (size_t)cnd * DIM) + sub * 4;
        const float4* hp = (const float4*)(h2prev + (size_t)b * HDIM) + sub * 4;
        float a = 0.f;
#pragma unroll
        for (int ii = 0; ii < 4; ++ii) {
            const float4 wv = wp[ii], hv = hp[ii];
            a = fmaf(hv.x, wv.x, fmaf(hv.y, wv.y, fmaf(hv.z, wv.z, fmaf(hv.w, wv.w, a))));
        }
#pragma unroll
        for (int m = 1; m < 32; m <<= 1) a += __shfl_xor(a, m);
        if (sub == 0) e8[gp] = a + bo[cnd];
    }
    __syncthreads();
    if (tid == 0) {
        float lv5[TOPKN]; int li5[TOPKN];
#pragma unroll
        for (int q = 0; q < TOPKN; ++q) { lv5[q] = -INFINITY; li5[q] = 0x7fffffff; }
#pragma unroll
        for (int q = 0; q < CAND; ++q) ins5(lv5, li5, e8[q], c8[q]);
        const int ridx = rix[(t - 1) * BATCH + b];
        int sb = li5[0];
#pragma unroll
        for (int q = 1; q < TOPKN; ++q) if (ridx == q) sb = li5[q];
        selw[b] = (unsigned)sb;
    }
}

struct GateLDS {
    float er[BATCH][516];
    float xgs[BATCH][6];
    int   sel[BATCH];
};

static __global__ void __launch_bounds__(NTHR, 1)
kGate(int t, const float* __restrict__ E, const float* __restrict__ WxT,
      const float* __restrict__ b_i, const float* __restrict__ ctx,
      const unsigned* __restrict__ selw, const float* __restrict__ hg,
      const float* __restrict__ h2prev, float* __restrict__ h2cur)
{
    extern __shared__ char raw[];
    GateLDS& s = *(GateLDS*)raw;
    const int j = blockIdx.x, tid = threadIdx.x;
    if (tid < BATCH)
        s.sel[tid] = (t == 0) ? BOSTOK : (int)selw[tid];
    __syncthreads();
    {
        const int b = tid >> 3, ch = tid & 7;
        const float4* src = (const float4*)(E + (size_t)s.sel[b] * DIM) + ch * 16;
        float* dst = &s.er[b][ch * 64];
#pragma unroll
        for (int i = 0; i < 16; ++i) {
            float4 v = src[i];
            v.x = v.x > 0.f ? v.x : ALPHA * v.x;
            v.y = v.y > 0.f ? v.y : ALPHA * v.y;
            v.z = v.z > 0.f ? v.z : ALPHA * v.z;
            v.w = v.w > 0.f ? v.w : ALPHA * v.w;
            *(float4*)(dst + 4 * i) = v;
        }
    }
    __syncthreads();
    if (tid < 192) {
        const int bb = tid & 31, pp = tid >> 5;
        const int gc = (pp >> 1) * HDIM + 2 * j + (pp & 1);
        const float4* er = (const float4*)&s.er[bb][0];
        const float4* wx = (const float4*)(WxT + (size_t)gc * DIM);
        float a0 = b_i[gc], a1 = 0.f, a2 = 0.f, a3 = 0.f;
#pragma unroll 4
        for (int i = 0; i < 128; i += 4) {
            const float4 e0 = er[i],     w0 = wx[i];
            const float4 e1 = er[i + 1], w1 = wx[i + 1];
            const float4 e2 = er[i + 2], w2 = wx[i + 2];
            const float4 e3 = er[i + 3], w3 = wx[i + 3];
            a0 = fmaf(e0.x, w0.x, fmaf(e0.y, w0.y, fmaf(e0.z, w0.z, fmaf(e0.w, w0.w, a0))));
            a1 = fmaf(e1.x, w1.x, fmaf(e1.y, w1.y, fmaf(e1.z, w1.z, fmaf(e1.w, w1.w, a1))));
            a2 = fmaf(e2.x, w2.x, fmaf(e2.y, w2.y, fmaf(e2.z, w2.z, fmaf(e2.w, w2.w, a2))));
            a3 = fmaf(e3.x, w3.x, fmaf(e3.y, w3.y, fmaf(e3.z, w3.z, fmaf(e3.w, w3.w, a3))));
        }
        s.xgs[bb][pp] = (a0 + a1) + (a2 + a3);
    }
    __syncthreads();
    if (tid < 64) {
        const int bb = tid >> 1, q = tid & 1, hc = 2 * j + q;
        const float hold = (t == 0) ? ctx[(size_t)bb * HDIM + hc]
                                    : h2prev[(size_t)bb * HDIM + hc];
        const float xz = s.xgs[bb][q], xr = s.xgs[bb][2 + q], xh = s.xgs[bb][4 + q];
        const float hz  = hg[(size_t)bb * G3H + hc];
        const float hr_ = hg[(size_t)bb * G3H + HDIM + hc];
        const float hh  = hg[(size_t)bb * G3H + 2 * HDIM + hc];
        const float z  = 1.f / (1.f + expf(-(xz + hz)));
        const float r  = 1.f / (1.f + expf(-(xr + hr_)));
        const float cd = tanhf(xh + r * hh);
        h2cur[(size_t)bb * HDIM + hc] = z * hold + (1.f - z) * cd;
    }
}

// =====================================================================
extern "C" void kernel_launch(void* const* d_in, const int* in_sizes, int n_in,
                              void* d_out, int out_size, void* d_ws, size_t ws_size,
                              hipStream_t stream) {
    (void)in_sizes; (void)n_in; (void)out_size;
    const float* E   = (const float*)d_in[0];
    const float* Wx  = (const float*)d_in[1];
    const float* U   = (const float*)d_in[2];
    const float* b_i = (const float*)d_in[3];
    const float* b_r = (const float*)d_in[4];
    const float* Wo  = (const float*)d_in[5];
    const float* bo  = (const float*)d_in[6];
    const float* ctx = (const float*)d_in[7];
    const int*   rix = (const int*)d_in[8];
    float* out = (float*)d_out;

    int dev = 0;
    (void)hipGetDevice(&dev);
    int numCU = 0;
    (void)hipDeviceGetAttribute(&numCU, hipDeviceAttributeMultiprocessorCount, dev);

    // ---- ws layout (bytes, 8B aligned; proven footprint) ----
    const size_t oWoPk = 0;            // 512*32000*2      = 32,768,000
    const size_t oWoT  = 32768000;     // 32000*512*4      = 65,536,000
    const size_t oUT   = 98304000;     // 1536*512*4       =  3,145,728
    const size_t oWxT  = 101449728;    // 1536*512*4       =  3,145,728
    const size_t oH2X  = 104595456;    // 2*32*512*4       =    131,072
    const size_t oHG   = 104726528;    // 32*1536*4        =    196,608
    const size_t oPVX  = 104923136;    // 32*250*5*8       =    320,000
    const size_t oBAR  = 105243136;    // selFW[32] u64 (256 B) + selw[32] u32
    const size_t need  = 105245312;

    if (ws_size < need) return;

    char* w = (char*)d_ws;
    unsigned* WoPk = (unsigned*)(w + oWoPk);
    float* WoT  = (float*)(w + oWoT);
    float* UT   = (float*)(w + oUT);
    float* WxT  = (float*)(w + oWxT);
    float* h2f  = (float*)(w + oH2X);
    float* hg   = (float*)(w + oHG);
    u64*   pvx  = (u64*)(w + oPVX);
    u64*      selFW = (u64*)(w + oBAR);
    unsigned* selw  = (unsigned*)(w + oBAR + 1024);

    const int GS_LDS   = (int)sizeof(GSLDS);
    const int GEMM_LDS = (int)sizeof(GemmLDS);
    const int GATE_LDS = (int)sizeof(GateLDS);
    (void)hipFuncSetAttribute((const void*)kGateSel,
                              hipFuncAttributeMaxDynamicSharedMemorySize, GS_LDS);
    (void)hipFuncSetAttribute((const void*)kGemmT<false>,
                              hipFuncAttributeMaxDynamicSharedMemorySize, GEMM_LDS);
    (void)hipFuncSetAttribute((const void*)kGemmT<true>,
                              hipFuncAttributeMaxDynamicSharedMemorySize, GEMM_LDS);
    (void)hipFuncSetAttribute((const void*)kGate,
                              hipFuncAttributeMaxDynamicSharedMemorySize, GATE_LDS);

    int maxBlk = 0;
    (void)hipOccupancyMaxActiveBlocksPerMultiprocessor(&maxBlk, kGateSel, NTHR, GS_LDS);
    const bool primary = (maxBlk >= 1) && (numCU >= NBLK);

    kProlog<<<dim3(NBLK), dim3(NTHR), 0, stream>>>(Wo, U, Wx, WoPk, WoT, UT, WxT);

    if (primary) {
        // 2 kernels/step: kGateSel (SEL+hg+gates) -> kGemm (logits+partials)
        (void)hipMemsetAsync((void*)selFW, 0, 256, stream);
        for (int t = 0; t < TSTEPS; ++t) {
            float*       h2cur  = h2f + ((t & 1) ^ 1) * (BATCH * HDIM);
            const float* h2prev = h2f + (t & 1) * (BATCH * HDIM);
            kGateSel<<<dim3(NBLK), dim3(NTHR), GS_LDS, stream>>>(
                t, E, WxT, UT, b_i, b_r, WoT, bo, rix, ctx, h2prev, h2cur, pvx, selFW);
            kGemmT<false><<<dim3(NBLK), dim3(NTHR), GEMM_LDS, stream>>>(
                t, WoPk, bo, UT, b_r, h2cur, out, hg, pvx);
        }
    } else {
        // proven round-7 3-kernel path
        kHg0<<<dim3(NBLK), dim3(NTHR), 0, stream>>>(ctx, UT, b_r, hg);
        for (int t = 0; t < TSTEPS; ++t) {
            float*       h2cur  = h2f + ((t & 1) ^ 1) * (BATCH * HDIM);
            const float* h2prev = h2f + (t & 1) * (BATCH * HDIM);
            if (t > 0)
                kSel<<<dim3(BATCH), dim3(NTHR), 0, stream>>>(t, WoT, bo, rix,
                                                             h2prev, pvx, selw);
            kGate<<<dim3(NBLK), dim3(NTHR), GATE_LDS, stream>>>(t, E, WxT, b_i, ctx,
                                                                selw, hg, h2prev, h2cur);
            kGemmT<true><<<dim3(NBLK), dim3(NTHR), GEMM_LDS, stream>>>(
                t, WoPk, bo, UT, b_r, h2cur, out, hg, pvx);
        }
    }
}